// Round 10
// baseline (819.081 us; speedup 1.0000x reference)
//
#include <hip/hip_runtime.h>

// Problem dims: B=2, T=4096, H=16, Dk=Dv=128. Chunked delta rule, L=64.
#define T_LEN 4096
#define H_N   16
#define DK    128
#define DV    128
#define LCH   64
#define NCH   64

typedef float f32x4 __attribute__((ext_vector_type(4)));
typedef short s16x8 __attribute__((ext_vector_type(8)));

// workspace layout per (head,chunk), bytes
#define OFF_U0 0        // [8 slices][64 rows][16 cols] f32 (sliced-contiguous)
#define OFF_W  32768    // 64x128 bf16, XOR-swizzled rows (negated W)
#define OFF_Q  49152    // 64x128 bf16, XOR-swizzled rows (gamma-less Q)
#define OFF_KD 65536    // 128x64 bf16, XOR-swizzled rows ([d][j] = rr_j k[j][d])
#define OFF_G  81920    // 64x64 bf16, XOR-swizzled rows
#define OFF_GM 90112    // 64 f32 (gamma_i = exp(cumsum ln a))
#define CH_B   90368ull
#define WS_NEED (2048ull * CH_B)

#define SWZ(row) (((row)&7) << 4)

__device__ __forceinline__ unsigned short f2b(float x) {
  unsigned u = __float_as_uint(x);
  return (unsigned short)((u + 0x7FFF + ((u >> 16) & 1)) >> 16);
}

// Async global->LDS (vmcnt; drained only by full __syncthreads)
#define GLDS16(gp, lp)                                                        \
  __builtin_amdgcn_global_load_lds(                                           \
      (const __attribute__((address_space(1))) void*)(gp),                    \
      (__attribute__((address_space(3))) void*)(lp), 16, 0, 0)
#define GLDS4(gp, lp)                                                         \
  __builtin_amdgcn_global_load_lds(                                           \
      (const __attribute__((address_space(1))) void*)(gp),                    \
      (__attribute__((address_space(3))) void*)(lp), 4, 0, 0)

// LDS-only barrier: orders ds_write/ds_read across waves WITHOUT draining
// vmcnt (staged global_load_lds stays in flight).
#define LBAR()                                                                \
  do {                                                                        \
    asm volatile("s_waitcnt lgkmcnt(0)" ::: "memory");                        \
    __builtin_amdgcn_s_barrier();                                             \
    __builtin_amdgcn_sched_barrier(0);                                        \
  } while (0)

// ---------------- Phase 1: per-(head,chunk) UT transform ----------------
// Register-column forward substitution: each thread owns ONE column of the
// fused RHS [diag(b)V | diag(b*gamma)K] (256 cols), held in y[64] registers.
// A streams from LDS as wave-uniform (broadcast, conflict-free) b128 reads.
//
// amdgpu_waves_per_eu(1,1): rounds 8/9 showed the allocator SPILLS y[64]
// (VGPR_Count=68, +700MB scratch HBM traffic) when it believes higher
// occupancy is reachable. launch_bounds' 2nd arg only sets the MIN (no-op
// at 1). Pinning max waves/EU = 1 removes the occupancy incentive -> y
// stays resident.
extern "C" __global__ void __launch_bounds__(256)
__attribute__((amdgpu_waves_per_eu(1, 1))) gdn_p1(
    const float* __restrict__ q, const float* __restrict__ k,
    const float* __restrict__ v, const float* __restrict__ al,
    const float* __restrict__ be, char* __restrict__ ws) {
  __shared__ __align__(16) unsigned char big[32768];   // Kb | Qb bf16 swizzled
  __shared__ __align__(16) float A_s[64 * 64];
  __shared__ float g_s[64], bb_s[64], sc_s[64], rr_s[64], bg_s[64];
  unsigned char* Kb = big;
  unsigned char* Qb = big + 16384;

  const int bid = blockIdx.x;
  const int bh = bid & 31, c = bid >> 5;
  const int b = bh >> 4, h = bh & 15;
  const int tid = threadIdx.x;
  const int t0 = c * LCH;
  char* wsc = ws + (size_t)(bh * 64 + c) * CH_B;

  // ---- gates: wave-0 parallel scan g = cumsum(ln a)
  if (tid < 64) {
    size_t gi = (size_t)(b * T_LEN + t0 + tid) * H_N + h;
    float x = __logf(al[gi]);
    float bbv = be[gi];
#pragma unroll
    for (int d = 1; d < 64; d <<= 1) {
      float yv = __shfl_up(x, d, 64);
      if (tid >= d) x += yv;
    }
    float tot = __shfl(x, 63, 64);
    float gam = __expf(x);
    g_s[tid] = x;
    bb_s[tid] = bbv;
    sc_s[tid] = gam;
    rr_s[tid] = __expf(tot - x);
    bg_s[tid] = bbv * gam;
    *(float*)(wsc + OFF_GM + tid * 4) = gam;
  }

  // ---- stage K,Q as bf16 (swizzled) in LDS; store Qbf to ws (swizzled)
  for (int idx = tid; idx < 1024; idx += 256) {
    int row = idx >> 4, grp = idx & 15;
    size_t go = ((size_t)(b * T_LEN + t0 + row) * H_N + h) * DK + grp * 8;
    float4 ka = *(const float4*)(k + go);
    float4 kb2 = *(const float4*)(k + go + 4);
    float4 qa = *(const float4*)(q + go);
    float4 qb2 = *(const float4*)(q + go + 4);
    union { unsigned short u[8]; uint4 v4; } tk, tq;
    tk.u[0] = f2b(ka.x); tk.u[1] = f2b(ka.y); tk.u[2] = f2b(ka.z); tk.u[3] = f2b(ka.w);
    tk.u[4] = f2b(kb2.x); tk.u[5] = f2b(kb2.y); tk.u[6] = f2b(kb2.z); tk.u[7] = f2b(kb2.w);
    tq.u[0] = f2b(qa.x); tq.u[1] = f2b(qa.y); tq.u[2] = f2b(qa.z); tq.u[3] = f2b(qa.w);
    tq.u[4] = f2b(qb2.x); tq.u[5] = f2b(qb2.y); tq.u[6] = f2b(qb2.z); tq.u[7] = f2b(qb2.w);
    int la = (row * 256 + grp * 16) ^ SWZ(row);
    *(uint4*)(Kb + la) = tk.v4;
    *(uint4*)(Qb + la) = tq.v4;
    *(uint4*)(wsc + OFF_Q + la) = tq.v4;
  }
  __syncthreads();  // phase-1 LDS + staged K/Q visible

  // ---- KK^T and QK^T via MFMA; scale+mask -> A_s (f32 LDS), G (bf16 ws)
  const int w = tid >> 6, l = tid & 63, li = l & 15, hi = l >> 4;
  f32x4 aK[4], aQ[4];
#pragma unroll
  for (int jt = 0; jt < 4; ++jt) { aK[jt] = (f32x4){0, 0, 0, 0}; aQ[jt] = (f32x4){0, 0, 0, 0}; }
#pragma unroll
  for (int ks = 0; ks < 4; ++ks) {
    int rowA = 16 * w + li;
    int oa = (rowA * 256 + ks * 64 + hi * 16) ^ SWZ(rowA);
    s16x8 fa = *(const s16x8*)(Kb + oa);
    s16x8 fq = *(const s16x8*)(Qb + oa);
#pragma unroll
    for (int jt = 0; jt < 4; ++jt) {
      int rowB = 16 * jt + li;
      s16x8 fb = *(const s16x8*)(Kb + ((rowB * 256 + ks * 64 + hi * 16) ^ SWZ(rowB)));
      aK[jt] = __builtin_amdgcn_mfma_f32_16x16x32_bf16(fa, fb, aK[jt], 0, 0, 0);
      aQ[jt] = __builtin_amdgcn_mfma_f32_16x16x32_bf16(fq, fb, aQ[jt], 0, 0, 0);
    }
  }
#pragma unroll
  for (int jt = 0; jt < 4; ++jt)
#pragma unroll
    for (int r = 0; r < 4; ++r) {
      int i = 16 * w + hi * 4 + r, j = 16 * jt + li;   // C layout (m89)
      float e = __expf(g_s[i] - g_s[j]);
      A_s[i * 64 + j] = (j < i) ? bb_s[i] * e * aK[jt][r] : 0.f;
      *(unsigned short*)(wsc + OFF_G + ((i * 128 + j * 2) ^ SWZ(i))) =
          f2b((j <= i) ? e * aQ[jt][r] : 0.f);
    }

  // ---- per-column RHS into registers (+ Kdt emission for K columns)
  float y[64];
  if (tid < 128) {
    const int cc = tid;  // V column
    const float* vp = v + ((size_t)(b * T_LEN + t0) * H_N + h) * DV + cc;
#pragma unroll
    for (int j = 0; j < 64; ++j) y[j] = bb_s[j] * vp[(size_t)j * (H_N * DV)];
  } else {
    const int d = tid - 128;  // K column
    const float* kp = k + ((size_t)(b * T_LEN + t0) * H_N + h) * DK + d;
#pragma unroll
    for (int m = 0; m < 8; ++m) {
      float kv[8];
#pragma unroll
      for (int e = 0; e < 8; ++e) kv[e] = kp[(size_t)(m * 8 + e) * (H_N * DK)];
      union { unsigned u2[4]; uint4 v4; } t;
#pragma unroll
      for (int e = 0; e < 4; ++e)
        t.u2[e] = (unsigned)f2b(rr_s[m * 8 + 2 * e] * kv[2 * e]) |
                  ((unsigned)f2b(rr_s[m * 8 + 2 * e + 1] * kv[2 * e + 1]) << 16);
      *(uint4*)(wsc + OFF_KD + ((d * 128 + m * 16) ^ SWZ(d))) = t.v4;  // Kdt row d
#pragma unroll
      for (int e = 0; e < 8; ++e) y[m * 8 + e] = bg_s[m * 8 + e] * kv[e];
    }
  }
  __syncthreads();  // A_s visible

  // ---- fused forward substitution, all in registers, zero barriers
  const float* Af = A_s;
#pragma unroll
  for (int I = 0; I < 4; ++I) {
    if (I > 0) {
      // rows 16I..16I+15 -= A[row][0..16I) . y[0..16I)
#pragma unroll
      for (int r = 0; r < 16; ++r) {
        const int row = 16 * I + r;
        float a0 = 0.f, a1 = 0.f, a2 = 0.f, a3 = 0.f;
#pragma unroll
        for (int j4 = 0; j4 < 4 * I; ++j4) {
          f32x4 av = *(const f32x4*)(Af + row * 64 + j4 * 4);  // wave-uniform
          a0 = fmaf(av[0], y[j4 * 4 + 0], a0);
          a1 = fmaf(av[1], y[j4 * 4 + 1], a1);
          a2 = fmaf(av[2], y[j4 * 4 + 2], a2);
          a3 = fmaf(av[3], y[j4 * 4 + 3], a3);
        }
        y[row] -= (a0 + a1) + (a2 + a3);
      }
    }
    // diagonal 16x16 block, serial in r
#pragma unroll
    for (int r = 1; r < 16; ++r) {
      const int row = 16 * I + r;
      float tacc0 = 0.f, tacc1 = 0.f;
#pragma unroll
      for (int m = 0; m < (r + 3) / 4; ++m) {
        f32x4 av = *(const f32x4*)(Af + row * 64 + 16 * I + m * 4);
#pragma unroll
        for (int e = 0; e < 4; ++e) {
          const int j = m * 4 + e;
          if (j < r) {
            if (j & 1) tacc1 = fmaf(av[e], y[16 * I + j], tacc1);
            else       tacc0 = fmaf(av[e], y[16 * I + j], tacc0);
          }
        }
      }
      y[row] -= tacc0 + tacc1;
    }
  }

  // ---- write results: U0 (f32 sliced) / W (negated bf16, swizzled)
  if (tid < 128) {
    const int cc = tid;
    char* up = wsc + OFF_U0 + (cc >> 4) * 4096 + (cc & 15) * 4;
#pragma unroll
    for (int j = 0; j < 64; ++j) *(float*)(up + j * 64) = y[j];
  } else {
    const int d = tid - 128;
#pragma unroll
    for (int j = 0; j < 64; ++j)
      *(unsigned short*)(wsc + OFF_W + ((j * 256 + d * 2) ^ SWZ(j))) = f2b(-y[j]);
  }
}

// ---------------- Phase 2: serial chunk recurrence, staged MFMA ----------
extern "C" __global__ void __launch_bounds__(256, 1) gdn_p2(
    const float* __restrict__ S0, float* __restrict__ out,
    const char* __restrict__ ws) {
  __shared__ unsigned char Wb[2][16384];
  __shared__ unsigned char Qb[2][16384];
  __shared__ unsigned char KDb[2][16384];
  __shared__ unsigned char Gb[2][8192];
  __shared__ float U0s[2][1024];
  __shared__ float gam[2][64];
  __shared__ unsigned char Stb[4096];
  __shared__ unsigned char Ytb[2048];

  const int bid = blockIdx.x;
  const int bh = bid & 31, s = bid >> 5;   // siblings share (bid mod 8) -> XCD
  const int b = bh >> 4, h = bh & 15;
  const int tid = threadIdx.x;
  const int w = tid >> 6, lane = tid & 63, li = lane & 15, hi = lane >> 4;
  const char* wsbase = ws + (size_t)bh * 64 * CH_B;

#define STG(CI, P)                                                            \
  do {                                                                        \
    const char* c_ = wsbase + (size_t)(CI) * CH_B;                            \
    _Pragma("unroll") for (int j_ = 0; j_ < 4; ++j_) {                        \
      GLDS16(c_ + OFF_W + j_ * 4096 + tid * 16, &Wb[P][j_ * 4096 + w * 1024]); \
      GLDS16(c_ + OFF_Q + j_ * 4096 + tid * 16, &Qb[P][j_ * 4096 + w * 1024]); \
      GLDS16(c_ + OFF_KD + j_ * 4096 + tid * 16, &KDb[P][j_ * 4096 + w * 1024]); \
    }                                                                         \
    _Pragma("unroll") for (int j_ = 0; j_ < 2; ++j_)                          \
      GLDS16(c_ + OFF_G + j_ * 4096 + tid * 16, &Gb[P][j_ * 4096 + w * 1024]); \
    GLDS16(c_ + OFF_U0 + s * 4096 + tid * 16,                                 \
           (unsigned char*)U0s[P] + w * 1024);                                \
    if (w == 0) GLDS4(c_ + OFF_GM + lane * 4, &gam[P][0]);                    \
  } while (0)

  float S[2][4];
#pragma unroll
  for (int t = 0; t < 2; ++t)
#pragma unroll
    for (int r = 0; r < 4; ++r) {
      int d = (w + 4 * t) * 16 + hi * 4 + r;
      S[t][r] = S0[((size_t)bh * 128 + d) * 128 + s * 16 + li];
    }
#define WRITE_ST()                                                            \
  do {                                                                        \
    _Pragma("unroll") for (int t = 0; t < 2; ++t)                             \
        _Pragma("unroll") for (int r = 0; r < 4; r += 2) {                    \
      int d = (w + 4 * t) * 16 + hi * 4 + r;                                  \
      unsigned pk = (unsigned)f2b(S[t][r]) | ((unsigned)f2b(S[t][r + 1]) << 16); \
      *(unsigned*)(Stb + ((li * 256 + d * 2) ^ SWZ(li))) = pk;                \
    }                                                                         \
  } while (0)

  STG(0, 0);
  WRITE_ST();
  __syncthreads();

#pragma unroll 1
  for (int c = 0; c < NCH; ++c) {
    const int p = c & 1;
    if (c + 1 < NCH) STG(c + 1, p ^ 1);

    s16x8 sfb[4];
#pragma unroll
    for (int ks = 0; ks < 4; ++ks)
      sfb[ks] = *(const s16x8*)(Stb + ((li * 256 + ks * 64 + hi * 16) ^ SWZ(li)));

    f32x4 Y;
#pragma unroll
    for (int r = 0; r < 4; ++r) Y[r] = U0s[p][(16 * w + hi * 4 + r) * 16 + li];
#pragma unroll
    for (int ks = 0; ks < 4; ++ks) {
      s16x8 fa = *(const s16x8*)(Wb[p] + (((16 * w + li) * 256 + ks * 64 + hi * 16) ^ SWZ(li)));
      Y = __builtin_amdgcn_mfma_f32_16x16x32_bf16(fa, sfb[ks], Y, 0, 0, 0);
    }
#pragma unroll
    for (int r = 0; r < 4; r += 2) {
      int j = 16 * w + hi * 4 + r;
      unsigned pk = (unsigned)f2b(Y[r]) | ((unsigned)f2b(Y[r + 1]) << 16);
      *(unsigned*)(Ytb + ((li * 128 + j * 2) ^ SWZ(li))) = pk;
    }
    LBAR();

    f32x4 O = {0, 0, 0, 0};
#pragma unroll
    for (int ks = 0; ks < 4; ++ks) {
      s16x8 fa = *(const s16x8*)(Qb[p] + (((16 * w + li) * 256 + ks * 64 + hi * 16) ^ SWZ(li)));
      O = __builtin_amdgcn_mfma_f32_16x16x32_bf16(fa, sfb[ks], O, 0, 0, 0);
    }
    s16x8 yfb[2];
#pragma unroll
    for (int ks = 0; ks < 2; ++ks)
      yfb[ks] = *(const s16x8*)(Ytb + ((li * 128 + ks * 64 + hi * 16) ^ SWZ(li)));
#pragma unroll
    for (int r = 0; r < 4; ++r) O[r] *= gam[p][16 * w + hi * 4 + r];
#pragma unroll
    for (int ks = 0; ks < 2; ++ks) {
      s16x8 fa = *(const s16x8*)(Gb[p] + (((16 * w + li) * 128 + ks * 64 + hi * 16) ^ SWZ(li)));
      O = __builtin_amdgcn_mfma_f32_16x16x32_bf16(fa, yfb[ks], O, 0, 0, 0);
    }
#pragma unroll
    for (int r = 0; r < 4; ++r) {
      size_t oi = ((size_t)(b * T_LEN + c * 64 + 16 * w + hi * 4 + r) * H_N + h) * DV + s * 16 + li;
      out[oi] = O[r];
    }

    float ge = gam[p][63];
#pragma unroll
    for (int t = 0; t < 2; ++t) {
      f32x4 acc;
#pragma unroll
      for (int r = 0; r < 4; ++r) acc[r] = ge * S[t][r];
#pragma unroll
      for (int ks = 0; ks < 2; ++ks) {
        s16x8 fa = *(const s16x8*)(KDb[p] + ((((w + 4 * t) * 16 + li) * 128 + ks * 64 + hi * 16) ^ SWZ(li)));
        acc = __builtin_amdgcn_mfma_f32_16x16x32_bf16(fa, yfb[ks], acc, 0, 0, 0);
      }
#pragma unroll
      for (int r = 0; r < 4; ++r) S[t][r] = acc[r];
    }
    LBAR();
    WRITE_ST();
    __syncthreads();
  }

#pragma unroll
  for (int t = 0; t < 2; ++t)
#pragma unroll
    for (int r = 0; r < 4; ++r) {
      int d = (w + 4 * t) * 16 + hi * 4 + r;
      out[(size_t)(2 * T_LEN * H_N * DV) + ((size_t)bh * 128 + d) * 128 + s * 16 + li] = S[t][r];
    }
}

// ---------------- Fallback (round-5 kernel, used only if ws too small) ----
#define COLS 16
#define CHUNK 16
#define STEP_B 8192u
#define AB_B 64u
#define OSTRIDE (H_N * DV)
template <int CTRL>
__device__ __forceinline__ float dpp_add(float x) {
  int y = __builtin_amdgcn_update_dpp(0, __float_as_int(x), CTRL, 0xF, 0xF, true);
  return x + __int_as_float(y);
}
__device__ __forceinline__ float red16(float x) {
  x = dpp_add<0xB1>(x); x = dpp_add<0x4E>(x);
  x = dpp_add<0x124>(x); x = dpp_add<0x128>(x);
  return x;
}
extern "C" __global__ void __launch_bounds__(256, 1) gdn_fallback(
    const float* __restrict__ q, const float* __restrict__ k,
    const float* __restrict__ v, const float* __restrict__ al,
    const float* __restrict__ be, const float* __restrict__ S0,
    float* __restrict__ out) {
  __shared__ float kb[2][CHUNK * DK];
  __shared__ float qb[2][CHUNK * DK];
  __shared__ float vb[2][CHUNK * COLS];
  __shared__ float abuf[2][64];
  __shared__ float bbuf[2][64];
  const int bid = blockIdx.x;
  const int bh = bid & 31, g = bid >> 5;
  const int b = bh >> 4, h = bh & 15;
  const int tid = threadIdx.x;
  const int cl = tid >> 4, li = tid & 15, lane = tid & 63, wid = tid >> 6;
  const int col = g * COLS + cl, d0 = li * 8;
  const size_t bh_qk = ((size_t)b * T_LEN * H_N + h) * DK;
  const size_t bh_v = ((size_t)b * T_LEN * H_N + h) * DV;
  const size_t bh_ab = (size_t)b * T_LEN * H_N + h;
  const int fo0 = wid * 2048 + lane * 16, fo1 = fo0 + 1024;
  const char* kg0 = (const char*)(k + bh_qk) + (size_t)(fo0 >> 9) * STEP_B + (fo0 & 511);
  const char* kg1 = (const char*)(k + bh_qk) + (size_t)(fo1 >> 9) * STEP_B + (fo1 & 511);
  const char* qg0 = (const char*)(q + bh_qk) + (size_t)(fo0 >> 9) * STEP_B + (fo0 & 511);
  const char* qg1 = (const char*)(q + bh_qk) + (size_t)(fo1 >> 9) * STEP_B + (fo1 & 511);
  const int fv = lane * 16;
  const char* vg = (const char*)(v + bh_v + g * COLS) + (size_t)(fv >> 6) * STEP_B + (fv & 63);
  const int lcl = lane < 16 ? lane : 15;
  const char* ag = (const char*)(al + bh_ab) + (size_t)lcl * AB_B;
  const char* bg = (const char*)(be + bh_ab) + (size_t)lcl * AB_B;
#define STAGEF(CI, P) do { \
    const size_t off = (size_t)(CI) * (CHUNK * STEP_B); \
    const size_t offab = (size_t)(CI) * (CHUNK * AB_B); \
    GLDS16(kg0 + off, &kb[P][wid * 512]); GLDS16(kg1 + off, &kb[P][wid * 512 + 256]); \
    GLDS16(qg0 + off, &qb[P][wid * 512]); GLDS16(qg1 + off, &qb[P][wid * 512 + 256]); \
    if (wid == 0) GLDS16(vg + off, &vb[P][0]); \
    else if (wid == 1) GLDS4(ag + offab, &abuf[P][0]); \
    else if (wid == 2) GLDS4(bg + offab, &bbuf[P][0]); \
  } while (0)
  float sv[8];
  const float* s0p = S0 + ((size_t)(b * H_N + h) * DK + d0) * DV + col;
#pragma unroll
  for (int j = 0; j < 8; ++j) sv[j] = s0p[(size_t)j * DV];
  STAGEF(0, 0);
  __syncthreads();
  float* op = out + bh_v + col;
  for (int ci = 0; ci < T_LEN / CHUNK; ++ci) {
    const int p = ci & 1;
    if (ci + 1 < T_LEN / CHUNK) STAGEF(ci + 1, p ^ 1);
    const float* kc = kb[p]; const float* qc = qb[p]; const float* vc = vb[p];
    const float* ac = abuf[p]; const float* bc = bbuf[p];
#pragma unroll
    for (int j = 0; j < CHUNK; ++j) {
      f32x4 kA = *(const f32x4*)(kc + j * DK + d0);
      f32x4 kB = *(const f32x4*)(kc + j * DK + d0 + 4);
      f32x4 qA = *(const f32x4*)(qc + j * DK + d0);
      f32x4 qB = *(const f32x4*)(qc + j * DK + d0 + 4);
      float vv = vc[j * COLS + cl], aa = ac[j], bv = bc[j];
      float kk[8] = {kA[0], kA[1], kA[2], kA[3], kB[0], kB[1], kB[2], kB[3]};
      float qq[8] = {qA[0], qA[1], qA[2], qA[3], qB[0], qB[1], qB[2], qB[3]};
      float pk0 = kk[0] * sv[0], pk1 = kk[1] * sv[1];
      float pu0 = qq[0] * sv[0], pu1 = qq[1] * sv[1];
      float pg0 = kk[0] * qq[0], pg1 = kk[1] * qq[1];
#pragma unroll
      for (int m = 2; m < 8; m += 2) {
        pk0 = fmaf(kk[m], sv[m], pk0); pk1 = fmaf(kk[m + 1], sv[m + 1], pk1);
        pu0 = fmaf(qq[m], sv[m], pu0); pu1 = fmaf(qq[m + 1], sv[m + 1], pu1);
        pg0 = fmaf(kk[m], qq[m], pg0); pg1 = fmaf(kk[m + 1], qq[m + 1], pg1);
      }
      float pk = red16(pk0 + pk1), pu = red16(pu0 + pu1), pg = red16(pg0 + pg1);
      float tmp = fmaf(-(bv * aa), pk, bv * vv);
#pragma unroll
      for (int m = 0; m < 8; ++m) sv[m] = fmaf(aa, sv[m], kk[m] * tmp);
      if (li == 0) op[(size_t)(ci * CHUNK + j) * OSTRIDE] = fmaf(pg, tmp, aa * pu);
    }
    __syncthreads();
  }
  float* sf = out + (size_t)2 * T_LEN * H_N * DV + ((size_t)(b * H_N + h) * DK + d0) * DV + col;
#pragma unroll
  for (int j = 0; j < 8; ++j) sf[(size_t)j * DV] = sv[j];
}

extern "C" void kernel_launch(void* const* d_in, const int* in_sizes, int n_in,
                              void* d_out, int out_size, void* d_ws,
                              size_t ws_size, hipStream_t stream) {
  const float* q = (const float*)d_in[0];
  const float* k = (const float*)d_in[1];
  const float* v = (const float*)d_in[2];
  const float* al = (const float*)d_in[3];
  const float* be = (const float*)d_in[4];
  const float* S0 = (const float*)d_in[5];
  float* out = (float*)d_out;

  if (ws_size >= WS_NEED) {
    gdn_p1<<<dim3(2048), dim3(256), 0, stream>>>(q, k, v, al, be, (char*)d_ws);
    gdn_p2<<<dim3(256), dim3(256), 0, stream>>>(S0, out, (const char*)d_ws);
  } else {
    gdn_fallback<<<dim3(256), dim3(256), 0, stream>>>(q, k, v, al, be, S0, out);
  }
}

// Round 11
// 479.575 us; speedup vs baseline: 1.7079x; 1.7079x over previous
//
#include <hip/hip_runtime.h>

// Problem dims: B=2, T=4096, H=16, Dk=Dv=128. Chunked delta rule, L=64.
#define T_LEN 4096
#define H_N   16
#define DK    128
#define DV    128
#define LCH   64
#define NCH   64

typedef float f32x4 __attribute__((ext_vector_type(4)));
typedef short s16x8 __attribute__((ext_vector_type(8)));

// workspace layout per (head,chunk), bytes
#define OFF_U0 0        // [8 slices][64 rows][16 cols] f32 (sliced-contiguous)
#define OFF_W  32768    // 64x128 bf16, XOR-swizzled rows (negated W)
#define OFF_Q  49152    // 64x128 bf16, XOR-swizzled rows (gamma-less Q)
#define OFF_KD 65536    // 128x64 bf16, XOR-swizzled rows ([d][j] = rr_j k[j][d])
#define OFF_G  81920    // 64x64 bf16, XOR-swizzled rows
#define OFF_GM 90112    // 64 f32 (gamma_i = exp(cumsum ln a))
#define CH_B   90368ull
#define WS_NEED (2048ull * CH_B)

#define SWZ(row) (((row)&7) << 4)

__device__ __forceinline__ unsigned short f2b(float x) {
  unsigned u = __float_as_uint(x);
  return (unsigned short)((u + 0x7FFF + ((u >> 16) & 1)) >> 16);
}

// Async global->LDS (vmcnt; drained only by full __syncthreads)
#define GLDS16(gp, lp)                                                        \
  __builtin_amdgcn_global_load_lds(                                           \
      (const __attribute__((address_space(1))) void*)(gp),                    \
      (__attribute__((address_space(3))) void*)(lp), 16, 0, 0)
#define GLDS4(gp, lp)                                                         \
  __builtin_amdgcn_global_load_lds(                                           \
      (const __attribute__((address_space(1))) void*)(gp),                    \
      (__attribute__((address_space(3))) void*)(lp), 4, 0, 0)

// LDS-only barrier: orders ds_write/ds_read across waves WITHOUT draining
// vmcnt (staged global_load_lds stays in flight).
#define LBAR()                                                                \
  do {                                                                        \
    asm volatile("s_waitcnt lgkmcnt(0)" ::: "memory");                        \
    __builtin_amdgcn_s_barrier();                                             \
    __builtin_amdgcn_sched_barrier(0);                                        \
  } while (0)

// ---------------- Phase 1: per-(head,chunk) UT transform ----------------
// Register-column forward substitution: each thread owns ONE column of the
// fused RHS [diag(b)V | diag(b*gamma)K] (256 cols), held in y[64] registers.
//
// Round-10 counters: wave-uniform ds_read_b128 of A does NOT broadcast on
// gfx950 (3.2e8 conflict cycles ~= 75 cyc/read, full serialization). Uniform
// b32 DOES broadcast [m136]. Fix: volatile scalar f32 reads of A (volatile
// prevents the compiler re-fusing them into b128).
//
// amdgpu_waves_per_eu(1,3): max=3 caps the allocator's occupancy target
// (budget ~170 VGPR >= the ~132 this kernel needs) so y[64] stays RESIDENT
// (rounds 8/9: default heuristic spilled y for 8 waves/EU, +700MB scratch);
// unlike (1,1) (round 10) it does not inflate LDS to 113KB / 1 block/CU.
extern "C" __global__ void __launch_bounds__(256)
__attribute__((amdgpu_waves_per_eu(1, 3))) gdn_p1(
    const float* __restrict__ q, const float* __restrict__ k,
    const float* __restrict__ v, const float* __restrict__ al,
    const float* __restrict__ be, char* __restrict__ ws) {
  __shared__ __align__(16) unsigned char big[32768];   // Kb | Qb bf16 swizzled
  __shared__ __align__(16) float A_s[64 * 64];
  __shared__ float g_s[64], bb_s[64], sc_s[64], rr_s[64], bg_s[64];
  unsigned char* Kb = big;
  unsigned char* Qb = big + 16384;

  const int bid = blockIdx.x;
  const int bh = bid & 31, c = bid >> 5;
  const int b = bh >> 4, h = bh & 15;
  const int tid = threadIdx.x;
  const int t0 = c * LCH;
  char* wsc = ws + (size_t)(bh * 64 + c) * CH_B;

  // ---- gates: wave-0 parallel scan g = cumsum(ln a)
  if (tid < 64) {
    size_t gi = (size_t)(b * T_LEN + t0 + tid) * H_N + h;
    float x = __logf(al[gi]);
    float bbv = be[gi];
#pragma unroll
    for (int d = 1; d < 64; d <<= 1) {
      float yv = __shfl_up(x, d, 64);
      if (tid >= d) x += yv;
    }
    float tot = __shfl(x, 63, 64);
    float gam = __expf(x);
    g_s[tid] = x;
    bb_s[tid] = bbv;
    sc_s[tid] = gam;
    rr_s[tid] = __expf(tot - x);
    bg_s[tid] = bbv * gam;
    *(float*)(wsc + OFF_GM + tid * 4) = gam;
  }

  // ---- stage K,Q as bf16 (swizzled) in LDS; store Qbf to ws (swizzled)
  for (int idx = tid; idx < 1024; idx += 256) {
    int row = idx >> 4, grp = idx & 15;
    size_t go = ((size_t)(b * T_LEN + t0 + row) * H_N + h) * DK + grp * 8;
    float4 ka = *(const float4*)(k + go);
    float4 kb2 = *(const float4*)(k + go + 4);
    float4 qa = *(const float4*)(q + go);
    float4 qb2 = *(const float4*)(q + go + 4);
    union { unsigned short u[8]; uint4 v4; } tk, tq;
    tk.u[0] = f2b(ka.x); tk.u[1] = f2b(ka.y); tk.u[2] = f2b(ka.z); tk.u[3] = f2b(ka.w);
    tk.u[4] = f2b(kb2.x); tk.u[5] = f2b(kb2.y); tk.u[6] = f2b(kb2.z); tk.u[7] = f2b(kb2.w);
    tq.u[0] = f2b(qa.x); tq.u[1] = f2b(qa.y); tq.u[2] = f2b(qa.z); tq.u[3] = f2b(qa.w);
    tq.u[4] = f2b(qb2.x); tq.u[5] = f2b(qb2.y); tq.u[6] = f2b(qb2.z); tq.u[7] = f2b(qb2.w);
    int la = (row * 256 + grp * 16) ^ SWZ(row);
    *(uint4*)(Kb + la) = tk.v4;
    *(uint4*)(Qb + la) = tq.v4;
    *(uint4*)(wsc + OFF_Q + la) = tq.v4;
  }
  __syncthreads();  // phase-1 LDS + staged K/Q visible

  // ---- KK^T and QK^T via MFMA; scale+mask -> A_s (f32 LDS), G (bf16 ws)
  const int w = tid >> 6, l = tid & 63, li = l & 15, hi = l >> 4;
  f32x4 aK[4], aQ[4];
#pragma unroll
  for (int jt = 0; jt < 4; ++jt) { aK[jt] = (f32x4){0, 0, 0, 0}; aQ[jt] = (f32x4){0, 0, 0, 0}; }
#pragma unroll
  for (int ks = 0; ks < 4; ++ks) {
    int rowA = 16 * w + li;
    int oa = (rowA * 256 + ks * 64 + hi * 16) ^ SWZ(rowA);
    s16x8 fa = *(const s16x8*)(Kb + oa);
    s16x8 fq = *(const s16x8*)(Qb + oa);
#pragma unroll
    for (int jt = 0; jt < 4; ++jt) {
      int rowB = 16 * jt + li;
      s16x8 fb = *(const s16x8*)(Kb + ((rowB * 256 + ks * 64 + hi * 16) ^ SWZ(rowB)));
      aK[jt] = __builtin_amdgcn_mfma_f32_16x16x32_bf16(fa, fb, aK[jt], 0, 0, 0);
      aQ[jt] = __builtin_amdgcn_mfma_f32_16x16x32_bf16(fq, fb, aQ[jt], 0, 0, 0);
    }
  }
#pragma unroll
  for (int jt = 0; jt < 4; ++jt)
#pragma unroll
    for (int r = 0; r < 4; ++r) {
      int i = 16 * w + hi * 4 + r, j = 16 * jt + li;   // C layout (m89)
      float e = __expf(g_s[i] - g_s[j]);
      A_s[i * 64 + j] = (j < i) ? bb_s[i] * e * aK[jt][r] : 0.f;
      *(unsigned short*)(wsc + OFF_G + ((i * 128 + j * 2) ^ SWZ(i))) =
          f2b((j <= i) ? e * aQ[jt][r] : 0.f);
    }

  // ---- per-column RHS into registers (+ Kdt emission for K columns)
  float y[64];
  if (tid < 128) {
    const int cc = tid;  // V column
    const float* vp = v + ((size_t)(b * T_LEN + t0) * H_N + h) * DV + cc;
#pragma unroll
    for (int j = 0; j < 64; ++j) y[j] = bb_s[j] * vp[(size_t)j * (H_N * DV)];
  } else {
    const int d = tid - 128;  // K column
    const float* kp = k + ((size_t)(b * T_LEN + t0) * H_N + h) * DK + d;
#pragma unroll
    for (int m = 0; m < 8; ++m) {
      float kv[8];
#pragma unroll
      for (int e = 0; e < 8; ++e) kv[e] = kp[(size_t)(m * 8 + e) * (H_N * DK)];
      union { unsigned u2[4]; uint4 v4; } t;
#pragma unroll
      for (int e = 0; e < 4; ++e)
        t.u2[e] = (unsigned)f2b(rr_s[m * 8 + 2 * e] * kv[2 * e]) |
                  ((unsigned)f2b(rr_s[m * 8 + 2 * e + 1] * kv[2 * e + 1]) << 16);
      *(uint4*)(wsc + OFF_KD + ((d * 128 + m * 16) ^ SWZ(d))) = t.v4;  // Kdt row d
#pragma unroll
      for (int e = 0; e < 8; ++e) y[m * 8 + e] = bg_s[m * 8 + e] * kv[e];
    }
  }
  __syncthreads();  // A_s visible

  // ---- fused forward substitution, all in registers, zero barriers.
  // A reads: volatile scalar f32 -> uniform ds_read_b32 (broadcasts free);
  // volatile prevents re-fusing into ds_read_b128 (serializes, round 10).
  const volatile float* Af = A_s;
#pragma unroll
  for (int I = 0; I < 4; ++I) {
    if (I > 0) {
      // rows 16I..16I+15 -= A[row][0..16I) . y[0..16I)
#pragma unroll
      for (int r = 0; r < 16; ++r) {
        const int row = 16 * I + r;
        float a0 = 0.f, a1 = 0.f, a2 = 0.f, a3 = 0.f;
#pragma unroll
        for (int j4 = 0; j4 < 4 * I; ++j4) {
          float v0 = Af[row * 64 + j4 * 4 + 0];
          float v1 = Af[row * 64 + j4 * 4 + 1];
          float v2 = Af[row * 64 + j4 * 4 + 2];
          float v3 = Af[row * 64 + j4 * 4 + 3];
          a0 = fmaf(v0, y[j4 * 4 + 0], a0);
          a1 = fmaf(v1, y[j4 * 4 + 1], a1);
          a2 = fmaf(v2, y[j4 * 4 + 2], a2);
          a3 = fmaf(v3, y[j4 * 4 + 3], a3);
        }
        y[row] -= (a0 + a1) + (a2 + a3);
      }
    }
    // diagonal 16x16 block, serial in r
#pragma unroll
    for (int r = 1; r < 16; ++r) {
      const int row = 16 * I + r;
      float tacc0 = 0.f, tacc1 = 0.f;
#pragma unroll
      for (int j = 0; j < r; ++j) {
        float av = Af[row * 64 + 16 * I + j];
        if (j & 1) tacc1 = fmaf(av, y[16 * I + j], tacc1);
        else       tacc0 = fmaf(av, y[16 * I + j], tacc0);
      }
      y[row] -= tacc0 + tacc1;
    }
  }

  // ---- write results: U0 (f32 sliced) / W (negated bf16, swizzled)
  if (tid < 128) {
    const int cc = tid;
    char* up = wsc + OFF_U0 + (cc >> 4) * 4096 + (cc & 15) * 4;
#pragma unroll
    for (int j = 0; j < 64; ++j) *(float*)(up + j * 64) = y[j];
  } else {
    const int d = tid - 128;
#pragma unroll
    for (int j = 0; j < 64; ++j)
      *(unsigned short*)(wsc + OFF_W + ((j * 256 + d * 2) ^ SWZ(j))) = f2b(-y[j]);
  }
}

// ---------------- Phase 2: serial chunk recurrence, staged MFMA ----------
extern "C" __global__ void __launch_bounds__(256, 1) gdn_p2(
    const float* __restrict__ S0, float* __restrict__ out,
    const char* __restrict__ ws) {
  __shared__ unsigned char Wb[2][16384];
  __shared__ unsigned char Qb[2][16384];
  __shared__ unsigned char KDb[2][16384];
  __shared__ unsigned char Gb[2][8192];
  __shared__ float U0s[2][1024];
  __shared__ float gam[2][64];
  __shared__ unsigned char Stb[4096];
  __shared__ unsigned char Ytb[2048];

  const int bid = blockIdx.x;
  const int bh = bid & 31, s = bid >> 5;   // siblings share (bid mod 8) -> XCD
  const int b = bh >> 4, h = bh & 15;
  const int tid = threadIdx.x;
  const int w = tid >> 6, lane = tid & 63, li = lane & 15, hi = lane >> 4;
  const char* wsbase = ws + (size_t)bh * 64 * CH_B;

#define STG(CI, P)                                                            \
  do {                                                                        \
    const char* c_ = wsbase + (size_t)(CI) * CH_B;                            \
    _Pragma("unroll") for (int j_ = 0; j_ < 4; ++j_) {                        \
      GLDS16(c_ + OFF_W + j_ * 4096 + tid * 16, &Wb[P][j_ * 4096 + w * 1024]); \
      GLDS16(c_ + OFF_Q + j_ * 4096 + tid * 16, &Qb[P][j_ * 4096 + w * 1024]); \
      GLDS16(c_ + OFF_KD + j_ * 4096 + tid * 16, &KDb[P][j_ * 4096 + w * 1024]); \
    }                                                                         \
    _Pragma("unroll") for (int j_ = 0; j_ < 2; ++j_)                          \
      GLDS16(c_ + OFF_G + j_ * 4096 + tid * 16, &Gb[P][j_ * 4096 + w * 1024]); \
    GLDS16(c_ + OFF_U0 + s * 4096 + tid * 16,                                 \
           (unsigned char*)U0s[P] + w * 1024);                                \
    if (w == 0) GLDS4(c_ + OFF_GM + lane * 4, &gam[P][0]);                    \
  } while (0)

  float S[2][4];
#pragma unroll
  for (int t = 0; t < 2; ++t)
#pragma unroll
    for (int r = 0; r < 4; ++r) {
      int d = (w + 4 * t) * 16 + hi * 4 + r;
      S[t][r] = S0[((size_t)bh * 128 + d) * 128 + s * 16 + li];
    }
#define WRITE_ST()                                                            \
  do {                                                                        \
    _Pragma("unroll") for (int t = 0; t < 2; ++t)                             \
        _Pragma("unroll") for (int r = 0; r < 4; r += 2) {                    \
      int d = (w + 4 * t) * 16 + hi * 4 + r;                                  \
      unsigned pk = (unsigned)f2b(S[t][r]) | ((unsigned)f2b(S[t][r + 1]) << 16); \
      *(unsigned*)(Stb + ((li * 256 + d * 2) ^ SWZ(li))) = pk;                \
    }                                                                         \
  } while (0)

  STG(0, 0);
  WRITE_ST();
  __syncthreads();

#pragma unroll 1
  for (int c = 0; c < NCH; ++c) {
    const int p = c & 1;
    if (c + 1 < NCH) STG(c + 1, p ^ 1);

    s16x8 sfb[4];
#pragma unroll
    for (int ks = 0; ks < 4; ++ks)
      sfb[ks] = *(const s16x8*)(Stb + ((li * 256 + ks * 64 + hi * 16) ^ SWZ(li)));

    f32x4 Y;
#pragma unroll
    for (int r = 0; r < 4; ++r) Y[r] = U0s[p][(16 * w + hi * 4 + r) * 16 + li];
#pragma unroll
    for (int ks = 0; ks < 4; ++ks) {
      s16x8 fa = *(const s16x8*)(Wb[p] + (((16 * w + li) * 256 + ks * 64 + hi * 16) ^ SWZ(li)));
      Y = __builtin_amdgcn_mfma_f32_16x16x32_bf16(fa, sfb[ks], Y, 0, 0, 0);
    }
#pragma unroll
    for (int r = 0; r < 4; r += 2) {
      int j = 16 * w + hi * 4 + r;
      unsigned pk = (unsigned)f2b(Y[r]) | ((unsigned)f2b(Y[r + 1]) << 16);
      *(unsigned*)(Ytb + ((li * 128 + j * 2) ^ SWZ(li))) = pk;
    }
    LBAR();

    f32x4 O = {0, 0, 0, 0};
#pragma unroll
    for (int ks = 0; ks < 4; ++ks) {
      s16x8 fa = *(const s16x8*)(Qb[p] + (((16 * w + li) * 256 + ks * 64 + hi * 16) ^ SWZ(li)));
      O = __builtin_amdgcn_mfma_f32_16x16x32_bf16(fa, sfb[ks], O, 0, 0, 0);
    }
    s16x8 yfb[2];
#pragma unroll
    for (int ks = 0; ks < 2; ++ks)
      yfb[ks] = *(const s16x8*)(Ytb + ((li * 128 + ks * 64 + hi * 16) ^ SWZ(li)));
#pragma unroll
    for (int r = 0; r < 4; ++r) O[r] *= gam[p][16 * w + hi * 4 + r];
#pragma unroll
    for (int ks = 0; ks < 2; ++ks) {
      s16x8 fa = *(const s16x8*)(Gb[p] + (((16 * w + li) * 128 + ks * 64 + hi * 16) ^ SWZ(li)));
      O = __builtin_amdgcn_mfma_f32_16x16x32_bf16(fa, yfb[ks], O, 0, 0, 0);
    }
#pragma unroll
    for (int r = 0; r < 4; ++r) {
      size_t oi = ((size_t)(b * T_LEN + c * 64 + 16 * w + hi * 4 + r) * H_N + h) * DV + s * 16 + li;
      out[oi] = O[r];
    }

    float ge = gam[p][63];
#pragma unroll
    for (int t = 0; t < 2; ++t) {
      f32x4 acc;
#pragma unroll
      for (int r = 0; r < 4; ++r) acc[r] = ge * S[t][r];
#pragma unroll
      for (int ks = 0; ks < 2; ++ks) {
        s16x8 fa = *(const s16x8*)(KDb[p] + ((((w + 4 * t) * 16 + li) * 128 + ks * 64 + hi * 16) ^ SWZ(li)));
        acc = __builtin_amdgcn_mfma_f32_16x16x32_bf16(fa, yfb[ks], acc, 0, 0, 0);
      }
#pragma unroll
      for (int r = 0; r < 4; ++r) S[t][r] = acc[r];
    }
    LBAR();
    WRITE_ST();
    __syncthreads();
  }

#pragma unroll
  for (int t = 0; t < 2; ++t)
#pragma unroll
    for (int r = 0; r < 4; ++r) {
      int d = (w + 4 * t) * 16 + hi * 4 + r;
      out[(size_t)(2 * T_LEN * H_N * DV) + ((size_t)bh * 128 + d) * 128 + s * 16 + li] = S[t][r];
    }
}

// ---------------- Fallback (round-5 kernel, used only if ws too small) ----
#define COLS 16
#define CHUNK 16
#define STEP_B 8192u
#define AB_B 64u
#define OSTRIDE (H_N * DV)
template <int CTRL>
__device__ __forceinline__ float dpp_add(float x) {
  int y = __builtin_amdgcn_update_dpp(0, __float_as_int(x), CTRL, 0xF, 0xF, true);
  return x + __int_as_float(y);
}
__device__ __forceinline__ float red16(float x) {
  x = dpp_add<0xB1>(x); x = dpp_add<0x4E>(x);
  x = dpp_add<0x124>(x); x = dpp_add<0x128>(x);
  return x;
}
extern "C" __global__ void __launch_bounds__(256, 1) gdn_fallback(
    const float* __restrict__ q, const float* __restrict__ k,
    const float* __restrict__ v, const float* __restrict__ al,
    const float* __restrict__ be, const float* __restrict__ S0,
    float* __restrict__ out) {
  __shared__ float kb[2][CHUNK * DK];
  __shared__ float qb[2][CHUNK * DK];
  __shared__ float vb[2][CHUNK * COLS];
  __shared__ float abuf[2][64];
  __shared__ float bbuf[2][64];
  const int bid = blockIdx.x;
  const int bh = bid & 31, g = bid >> 5;
  const int b = bh >> 4, h = bh & 15;
  const int tid = threadIdx.x;
  const int cl = tid >> 4, li = tid & 15, lane = tid & 63, wid = tid >> 6;
  const int col = g * COLS + cl, d0 = li * 8;
  const size_t bh_qk = ((size_t)b * T_LEN * H_N + h) * DK;
  const size_t bh_v = ((size_t)b * T_LEN * H_N + h) * DV;
  const size_t bh_ab = (size_t)b * T_LEN * H_N + h;
  const int fo0 = wid * 2048 + lane * 16, fo1 = fo0 + 1024;
  const char* kg0 = (const char*)(k + bh_qk) + (size_t)(fo0 >> 9) * STEP_B + (fo0 & 511);
  const char* kg1 = (const char*)(k + bh_qk) + (size_t)(fo1 >> 9) * STEP_B + (fo1 & 511);
  const char* qg0 = (const char*)(q + bh_qk) + (size_t)(fo0 >> 9) * STEP_B + (fo0 & 511);
  const char* qg1 = (const char*)(q + bh_qk) + (size_t)(fo1 >> 9) * STEP_B + (fo1 & 511);
  const int fv = lane * 16;
  const char* vg = (const char*)(v + bh_v + g * COLS) + (size_t)(fv >> 6) * STEP_B + (fv & 63);
  const int lcl = lane < 16 ? lane : 15;
  const char* ag = (const char*)(al + bh_ab) + (size_t)lcl * AB_B;
  const char* bg = (const char*)(be + bh_ab) + (size_t)lcl * AB_B;
#define STAGEF(CI, P) do { \
    const size_t off = (size_t)(CI) * (CHUNK * STEP_B); \
    const size_t offab = (size_t)(CI) * (CHUNK * AB_B); \
    GLDS16(kg0 + off, &kb[P][wid * 512]); GLDS16(kg1 + off, &kb[P][wid * 512 + 256]); \
    GLDS16(qg0 + off, &qb[P][wid * 512]); GLDS16(qg1 + off, &qb[P][wid * 512 + 256]); \
    if (wid == 0) GLDS16(vg + off, &vb[P][0]); \
    else if (wid == 1) GLDS4(ag + offab, &abuf[P][0]); \
    else if (wid == 2) GLDS4(bg + offab, &bbuf[P][0]); \
  } while (0)
  float sv[8];
  const float* s0p = S0 + ((size_t)(b * H_N + h) * DK + d0) * DV + col;
#pragma unroll
  for (int j = 0; j < 8; ++j) sv[j] = s0p[(size_t)j * DV];
  STAGEF(0, 0);
  __syncthreads();
  float* op = out + bh_v + col;
  for (int ci = 0; ci < T_LEN / CHUNK; ++ci) {
    const int p = ci & 1;
    if (ci + 1 < T_LEN / CHUNK) STAGEF(ci + 1, p ^ 1);
    const float* kc = kb[p]; const float* qc = qb[p]; const float* vc = vb[p];
    const float* ac = abuf[p]; const float* bc = bbuf[p];
#pragma unroll
    for (int j = 0; j < CHUNK; ++j) {
      f32x4 kA = *(const f32x4*)(kc + j * DK + d0);
      f32x4 kB = *(const f32x4*)(kc + j * DK + d0 + 4);
      f32x4 qA = *(const f32x4*)(qc + j * DK + d0);
      f32x4 qB = *(const f32x4*)(qc + j * DK + d0 + 4);
      float vv = vc[j * COLS + cl], aa = ac[j], bv = bc[j];
      float kk[8] = {kA[0], kA[1], kA[2], kA[3], kB[0], kB[1], kB[2], kB[3]};
      float qq[8] = {qA[0], qA[1], qA[2], qA[3], qB[0], qB[1], qB[2], qB[3]};
      float pk0 = kk[0] * sv[0], pk1 = kk[1] * sv[1];
      float pu0 = qq[0] * sv[0], pu1 = qq[1] * sv[1];
      float pg0 = kk[0] * qq[0], pg1 = kk[1] * qq[1];
#pragma unroll
      for (int m = 2; m < 8; m += 2) {
        pk0 = fmaf(kk[m], sv[m], pk0); pk1 = fmaf(kk[m + 1], sv[m + 1], pk1);
        pu0 = fmaf(qq[m], sv[m], pu0); pu1 = fmaf(qq[m + 1], sv[m + 1], pu1);
        pg0 = fmaf(kk[m], qq[m], pg0); pg1 = fmaf(kk[m + 1], qq[m + 1], pg1);
      }
      float pk = red16(pk0 + pk1), pu = red16(pu0 + pu1), pg = red16(pg0 + pg1);
      float tmp = fmaf(-(bv * aa), pk, bv * vv);
#pragma unroll
      for (int m = 0; m < 8; ++m) sv[m] = fmaf(aa, sv[m], kk[m] * tmp);
      if (li == 0) op[(size_t)(ci * CHUNK + j) * OSTRIDE] = fmaf(pg, tmp, aa * pu);
    }
    __syncthreads();
  }
  float* sf = out + (size_t)2 * T_LEN * H_N * DV + ((size_t)(b * H_N + h) * DK + d0) * DV + col;
#pragma unroll
  for (int j = 0; j < 8; ++j) sf[(size_t)j * DV] = sv[j];
}

extern "C" void kernel_launch(void* const* d_in, const int* in_sizes, int n_in,
                              void* d_out, int out_size, void* d_ws,
                              size_t ws_size, hipStream_t stream) {
  const float* q = (const float*)d_in[0];
  const float* k = (const float*)d_in[1];
  const float* v = (const float*)d_in[2];
  const float* al = (const float*)d_in[3];
  const float* be = (const float*)d_in[4];
  const float* S0 = (const float*)d_in[5];
  float* out = (float*)d_out;

  if (ws_size >= WS_NEED) {
    gdn_p1<<<dim3(2048), dim3(256), 0, stream>>>(q, k, v, al, be, (char*)d_ws);
    gdn_p2<<<dim3(256), dim3(256), 0, stream>>>(S0, out, (const char*)d_ws);
  } else {
    gdn_fallback<<<dim3(256), dim3(256), 0, stream>>>(q, k, v, al, be, S0, out);
  }
}

// Round 12
// 294.312 us; speedup vs baseline: 2.7830x; 1.6295x over previous
//
#include <hip/hip_runtime.h>

// Problem dims: B=2, T=4096, H=16, Dk=Dv=128. Chunked delta rule, L=64.
#define T_LEN 4096
#define H_N   16
#define DK    128
#define DV    128
#define LCH   64
#define NCH   64

typedef float f32x4 __attribute__((ext_vector_type(4)));
typedef short s16x8 __attribute__((ext_vector_type(8)));

// workspace layout per (head,chunk), bytes
#define OFF_U0 0        // [8 slices][64 rows][16 cols] f32 (sliced-contiguous)
#define OFF_W  32768    // 64x128 bf16, XOR-swizzled rows (negated W)
#define OFF_Q  49152    // 64x128 bf16, XOR-swizzled rows (gamma-less Q)
#define OFF_KD 65536    // 128x64 bf16, XOR-swizzled rows ([d][j] = rr_j k[j][d])
#define OFF_G  81920    // 64x64 bf16, XOR-swizzled rows
#define OFF_GM 90112    // 64 f32 (gamma_i = exp(cumsum ln a))
#define CH_B   90368ull
#define WS_NEED (2048ull * CH_B)

#define SWZ(row) (((row)&7) << 4)

// LDS strides (padded to kill bank conflicts; round-12 change)
#define AST 68    // A_s row stride in f32: banks differ by 4 per row -> free
#define RST 132   // RHS row stride in f32

__device__ __forceinline__ unsigned short f2b(float x) {
  unsigned u = __float_as_uint(x);
  return (unsigned short)((u + 0x7FFF + ((u >> 16) & 1)) >> 16);
}

// Async global->LDS (vmcnt; drained only by full __syncthreads)
#define GLDS16(gp, lp)                                                        \
  __builtin_amdgcn_global_load_lds(                                           \
      (const __attribute__((address_space(1))) void*)(gp),                    \
      (__attribute__((address_space(3))) void*)(lp), 16, 0, 0)
#define GLDS4(gp, lp)                                                         \
  __builtin_amdgcn_global_load_lds(                                           \
      (const __attribute__((address_space(1))) void*)(gp),                    \
      (__attribute__((address_space(3))) void*)(lp), 4, 0, 0)

// LDS-only barrier: orders ds_write/ds_read across waves WITHOUT draining
// vmcnt (staged global_load_lds stays in flight).
#define LBAR()                                                                \
  do {                                                                        \
    asm volatile("s_waitcnt lgkmcnt(0)" ::: "memory");                        \
    __builtin_amdgcn_s_barrier();                                             \
    __builtin_amdgcn_sched_barrier(0);                                        \
  } while (0)

// ---------------- Phase 1: per-(head,chunk) UT transform ----------------
__device__ void solve64(float* RHS, const float* A, int tid) {
  // (I+A) Y = RHS, A strictly lower 64x64 (stride AST); RHS stride RST.
#pragma unroll 1
  for (int I = 0; I < 4; ++I) {
    if (I > 0) {
      // rows [16I,16I+16) -= A[rows, 0:16I] * Y[0:16I]
      const int i2 = 16 * I + (tid >> 4), cg = tid & 15;
      float* rp = RHS + i2 * RST + cg * 8;
      f32x4 a0 = *(const f32x4*)(rp);
      f32x4 a1 = *(const f32x4*)(rp + 4);
      for (int j = 0; j < 16 * I; ++j) {
        float a = A[i2 * AST + j];              // 4 rows -> 4 banks: free
        const float* yp = RHS + j * RST + cg * 8;
        f32x4 y0 = *(const f32x4*)(yp);
        f32x4 y1 = *(const f32x4*)(yp + 4);
#pragma unroll
        for (int e = 0; e < 4; ++e) {
          a0[e] = fmaf(-a, y0[e], a0[e]);
          a1[e] = fmaf(-a, y1[e], a1[e]);
        }
      }
      *(f32x4*)(rp) = a0;
      *(f32x4*)(rp + 4) = a1;
      __syncthreads();
    }
    // diagonal 16x16 block, serial rows, 128 threads (1 col each)
    if (tid < 128) {
      const int col = tid;
      float y[16];
#pragma unroll
      for (int r = 0; r < 16; ++r) y[r] = RHS[(16 * I + r) * RST + col];
#pragma unroll
      for (int r = 1; r < 16; ++r) {
        float t0 = 0.f, t1 = 0.f;
#pragma unroll
        for (int j = 0; j < 15; ++j)
          if (j < r) {
            float av = A[(16 * I + r) * AST + 16 * I + j];  // uniform: bcast
            if (j & 1) t1 = fmaf(av, y[j], t1);
            else       t0 = fmaf(av, y[j], t0);
          }
        y[r] -= t0 + t1;
      }
#pragma unroll
      for (int r = 0; r < 16; ++r) RHS[(16 * I + r) * RST + col] = y[r];
    }
    __syncthreads();
  }
}

extern "C" __global__ void __launch_bounds__(256) gdn_p1(
    const float* __restrict__ q, const float* __restrict__ k,
    const float* __restrict__ v, const float* __restrict__ al,
    const float* __restrict__ be, char* __restrict__ ws) {
  __shared__ __align__(16) unsigned char big[34048];  // Kb|Qb; later RHS 64xRST f32
  __shared__ __align__(16) float A_s[64 * AST];
  __shared__ float g_s[64], bb_s[64], sc_s[64];
  unsigned char* Kb = big;            // 64x128 bf16, swizzled
  unsigned char* Qb = big + 16384;    // 64x128 bf16, swizzled
  float* RHS = (float*)big;           // 64xRST f32 (aliases Kb/Qb, used later)

  const int bid = blockIdx.x;
  const int bh = bid & 31, c = bid >> 5;
  const int b = bh >> 4, h = bh & 15;
  const int tid = threadIdx.x;
  const int t0 = c * LCH;
  char* wsc = ws + (size_t)(bh * 64 + c) * CH_B;

  // ---- gates: wave-0 Kogge-Stone scan g = cumsum(ln a); gamma = exp(g)
  if (tid < 64) {
    size_t gi = (size_t)(b * T_LEN + t0 + tid) * H_N + h;
    float x = __logf(al[gi]);
    bb_s[tid] = be[gi];
#pragma unroll
    for (int d = 1; d < 64; d <<= 1) {
      float yv = __shfl_up(x, d, 64);
      if (tid >= d) x += yv;
    }
    float gam = __expf(x);
    g_s[tid] = x;
    sc_s[tid] = gam;
    *(float*)(wsc + OFF_GM + tid * 4) = gam;
  }

  // ---- stage K,Q as bf16 (swizzled) in LDS; store Qbf to ws (swizzled)
  for (int idx = tid; idx < 1024; idx += 256) {
    int row = idx >> 4, grp = idx & 15;
    size_t go = ((size_t)(b * T_LEN + t0 + row) * H_N + h) * DK + grp * 8;
    float4 ka = *(const float4*)(k + go);
    float4 kb2 = *(const float4*)(k + go + 4);
    float4 qa = *(const float4*)(q + go);
    float4 qb2 = *(const float4*)(q + go + 4);
    union { unsigned short u[8]; uint4 v4; } tk, tq;
    tk.u[0] = f2b(ka.x); tk.u[1] = f2b(ka.y); tk.u[2] = f2b(ka.z); tk.u[3] = f2b(ka.w);
    tk.u[4] = f2b(kb2.x); tk.u[5] = f2b(kb2.y); tk.u[6] = f2b(kb2.z); tk.u[7] = f2b(kb2.w);
    tq.u[0] = f2b(qa.x); tq.u[1] = f2b(qa.y); tq.u[2] = f2b(qa.z); tq.u[3] = f2b(qa.w);
    tq.u[4] = f2b(qb2.x); tq.u[5] = f2b(qb2.y); tq.u[6] = f2b(qb2.z); tq.u[7] = f2b(qb2.w);
    int la = (row * 256 + grp * 16) ^ SWZ(row);
    *(uint4*)(Kb + la) = tk.v4;
    *(uint4*)(Qb + la) = tq.v4;
    *(uint4*)(wsc + OFF_Q + la) = tq.v4;
  }
  __syncthreads();  // gates + staged K/Q visible

  // ---- KK^T and QK^T via MFMA; scale+mask -> A_s (f32 LDS), G (bf16 ws)
  const int w = tid >> 6, l = tid & 63, li = l & 15, hi = l >> 4;
  f32x4 aK[4], aQ[4];
#pragma unroll
  for (int jt = 0; jt < 4; ++jt) { aK[jt] = (f32x4){0, 0, 0, 0}; aQ[jt] = (f32x4){0, 0, 0, 0}; }
#pragma unroll
  for (int ks = 0; ks < 4; ++ks) {
    int rowA = 16 * w + li;
    int oa = (rowA * 256 + ks * 64 + hi * 16) ^ SWZ(rowA);
    s16x8 fa = *(const s16x8*)(Kb + oa);
    s16x8 fq = *(const s16x8*)(Qb + oa);
#pragma unroll
    for (int jt = 0; jt < 4; ++jt) {
      int rowB = 16 * jt + li;
      s16x8 fb = *(const s16x8*)(Kb + ((rowB * 256 + ks * 64 + hi * 16) ^ SWZ(rowB)));
      aK[jt] = __builtin_amdgcn_mfma_f32_16x16x32_bf16(fa, fb, aK[jt], 0, 0, 0);
      aQ[jt] = __builtin_amdgcn_mfma_f32_16x16x32_bf16(fq, fb, aQ[jt], 0, 0, 0);
    }
  }
#pragma unroll
  for (int jt = 0; jt < 4; ++jt)
#pragma unroll
    for (int r = 0; r < 4; ++r) {
      int i = 16 * w + hi * 4 + r, j = 16 * jt + li;   // C layout (m89)
      float e = __expf(g_s[i] - g_s[j]);
      A_s[i * AST + j] = (j < i) ? bb_s[i] * e * aK[jt][r] : 0.f;
      *(unsigned short*)(wsc + OFF_G + ((i * 128 + j * 2) ^ SWZ(i))) =
          f2b((j <= i) ? e * aQ[jt][r] : 0.f);
    }
  __syncthreads();  // Kb/Qb reads done -> RHS may overwrite; A_s visible

  // ---- solve U0: RHS = diag(b) V; store sliced-contiguous f32
  for (int idx = tid; idx < 2048; idx += 256) {
    int row = idx >> 5, c4 = idx & 31;
    float4 vv = *(const float4*)(v + ((size_t)(b * T_LEN + t0 + row) * H_N + h) * DV + c4 * 4);
    float s = bb_s[row];
    float4 o = {s * vv.x, s * vv.y, s * vv.z, s * vv.w};
    *(float4*)(RHS + row * RST + c4 * 4) = o;
  }
  __syncthreads();
  solve64(RHS, A_s, tid);
  for (int idx = tid; idx < 2048; idx += 256) {
    int row = idx >> 5, c4 = idx & 31;
    *(float4*)(wsc + OFF_U0 + (c4 >> 2) * 4096 + row * 64 + (c4 & 3) * 16) =
        *(const float4*)(RHS + row * RST + c4 * 4);
  }
  __syncthreads();

  // ---- solve W: RHS = diag(b*gamma) K; store negated bf16 (swizzled)
  for (int idx = tid; idx < 2048; idx += 256) {
    int row = idx >> 5, c4 = idx & 31;
    float4 kv = *(const float4*)(k + ((size_t)(b * T_LEN + t0 + row) * H_N + h) * DK + c4 * 4);
    float s = bb_s[row] * sc_s[row];
    float4 o = {s * kv.x, s * kv.y, s * kv.z, s * kv.w};
    *(float4*)(RHS + row * RST + c4 * 4) = o;
  }
  __syncthreads();
  solve64(RHS, A_s, tid);
  for (int idx = tid; idx < 1024; idx += 256) {
    int row = idx >> 4, g8 = idx & 15;
    const float* p = RHS + row * RST + g8 * 8;
    union { unsigned short u[8]; uint4 v4; } t;
#pragma unroll
    for (int e = 0; e < 8; ++e) t.u[e] = f2b(-p[e]);
    *(uint4*)(wsc + OFF_W + ((row * 256 + g8 * 16) ^ SWZ(row))) = t.v4;
  }
  __syncthreads();

  // ---- Kdt[d][j] = exp(g63-g_j) * k[j][d] (swizzled rows of 128B)
  if (tid < 64) sc_s[tid] = __expf(g_s[63] - g_s[tid]);  // rr_j
  __syncthreads();
  float* Kf = (float*)big;  // 32 x 132 f32
#pragma unroll 1
  for (int p = 0; p < 2; ++p) {
    for (int idx = tid; idx < 1024; idx += 256) {
      int r = idx >> 5, c4 = idx & 31;
      float4 kv = *(const float4*)(k + ((size_t)(b * T_LEN + t0 + 32 * p + r) * H_N + h) * DK + c4 * 4);
      *(float4*)(Kf + r * 132 + c4 * 4) = kv;
    }
    __syncthreads();
#pragma unroll
    for (int m = 0; m < 16; ++m) {
      int flat = m * 256 + tid;            // 128 d x 32 j
      int j32 = flat & 31, d = flat >> 5;
      float val = sc_s[32 * p + j32] * Kf[j32 * 132 + d];
      *(unsigned short*)(wsc + OFF_KD + ((d * 128 + (32 * p + j32) * 2) ^ SWZ(d))) = f2b(val);
    }
    __syncthreads();
  }
}

// ---------------- Phase 2: serial chunk recurrence, staged MFMA ----------
extern "C" __global__ void __launch_bounds__(256, 1) gdn_p2(
    const float* __restrict__ S0, float* __restrict__ out,
    const char* __restrict__ ws) {
  __shared__ unsigned char Wb[2][16384];
  __shared__ unsigned char Qb[2][16384];
  __shared__ unsigned char KDb[2][16384];
  __shared__ unsigned char Gb[2][8192];
  __shared__ float U0s[2][1024];
  __shared__ float gam[2][64];
  __shared__ unsigned char Stb[4096];
  __shared__ unsigned char Ytb[2048];

  const int bid = blockIdx.x;
  const int bh = bid & 31, s = bid >> 5;   // siblings share (bid mod 8) -> XCD
  const int b = bh >> 4, h = bh & 15;
  const int tid = threadIdx.x;
  const int w = tid >> 6, lane = tid & 63, li = lane & 15, hi = lane >> 4;
  const char* wsbase = ws + (size_t)bh * 64 * CH_B;

#define STG(CI, P)                                                            \
  do {                                                                        \
    const char* c_ = wsbase + (size_t)(CI) * CH_B;                            \
    _Pragma("unroll") for (int j_ = 0; j_ < 4; ++j_) {                        \
      GLDS16(c_ + OFF_W + j_ * 4096 + tid * 16, &Wb[P][j_ * 4096 + w * 1024]); \
      GLDS16(c_ + OFF_Q + j_ * 4096 + tid * 16, &Qb[P][j_ * 4096 + w * 1024]); \
      GLDS16(c_ + OFF_KD + j_ * 4096 + tid * 16, &KDb[P][j_ * 4096 + w * 1024]); \
    }                                                                         \
    _Pragma("unroll") for (int j_ = 0; j_ < 2; ++j_)                          \
      GLDS16(c_ + OFF_G + j_ * 4096 + tid * 16, &Gb[P][j_ * 4096 + w * 1024]); \
    GLDS16(c_ + OFF_U0 + s * 4096 + tid * 16,                                 \
           (unsigned char*)U0s[P] + w * 1024);                                \
    if (w == 0) GLDS4(c_ + OFF_GM + lane * 4, &gam[P][0]);                    \
  } while (0)

  float S[2][4];
#pragma unroll
  for (int t = 0; t < 2; ++t)
#pragma unroll
    for (int r = 0; r < 4; ++r) {
      int d = (w + 4 * t) * 16 + hi * 4 + r;
      S[t][r] = S0[((size_t)bh * 128 + d) * 128 + s * 16 + li];
    }
#define WRITE_ST()                                                            \
  do {                                                                        \
    _Pragma("unroll") for (int t = 0; t < 2; ++t)                             \
        _Pragma("unroll") for (int r = 0; r < 4; r += 2) {                    \
      int d = (w + 4 * t) * 16 + hi * 4 + r;                                  \
      unsigned pk = (unsigned)f2b(S[t][r]) | ((unsigned)f2b(S[t][r + 1]) << 16); \
      *(unsigned*)(Stb + ((li * 256 + d * 2) ^ SWZ(li))) = pk;                \
    }                                                                         \
  } while (0)

  STG(0, 0);
  WRITE_ST();
  __syncthreads();

#pragma unroll 1
  for (int c = 0; c < NCH; ++c) {
    const int p = c & 1;
    if (c + 1 < NCH) STG(c + 1, p ^ 1);

    s16x8 sfb[4];
#pragma unroll
    for (int ks = 0; ks < 4; ++ks)
      sfb[ks] = *(const s16x8*)(Stb + ((li * 256 + ks * 64 + hi * 16) ^ SWZ(li)));

    f32x4 Y;
#pragma unroll
    for (int r = 0; r < 4; ++r) Y[r] = U0s[p][(16 * w + hi * 4 + r) * 16 + li];
#pragma unroll
    for (int ks = 0; ks < 4; ++ks) {
      s16x8 fa = *(const s16x8*)(Wb[p] + (((16 * w + li) * 256 + ks * 64 + hi * 16) ^ SWZ(li)));
      Y = __builtin_amdgcn_mfma_f32_16x16x32_bf16(fa, sfb[ks], Y, 0, 0, 0);
    }
#pragma unroll
    for (int r = 0; r < 4; r += 2) {
      int j = 16 * w + hi * 4 + r;
      unsigned pk = (unsigned)f2b(Y[r]) | ((unsigned)f2b(Y[r + 1]) << 16);
      *(unsigned*)(Ytb + ((li * 128 + j * 2) ^ SWZ(li))) = pk;
    }
    LBAR();

    f32x4 O = {0, 0, 0, 0};
#pragma unroll
    for (int ks = 0; ks < 4; ++ks) {
      s16x8 fa = *(const s16x8*)(Qb[p] + (((16 * w + li) * 256 + ks * 64 + hi * 16) ^ SWZ(li)));
      O = __builtin_amdgcn_mfma_f32_16x16x32_bf16(fa, sfb[ks], O, 0, 0, 0);
    }
    s16x8 yfb[2];
#pragma unroll
    for (int ks = 0; ks < 2; ++ks)
      yfb[ks] = *(const s16x8*)(Ytb + ((li * 128 + ks * 64 + hi * 16) ^ SWZ(li)));
#pragma unroll
    for (int r = 0; r < 4; ++r) O[r] *= gam[p][16 * w + hi * 4 + r];
#pragma unroll
    for (int ks = 0; ks < 2; ++ks) {
      s16x8 fa = *(const s16x8*)(Gb[p] + (((16 * w + li) * 128 + ks * 64 + hi * 16) ^ SWZ(li)));
      O = __builtin_amdgcn_mfma_f32_16x16x32_bf16(fa, yfb[ks], O, 0, 0, 0);
    }
#pragma unroll
    for (int r = 0; r < 4; ++r) {
      size_t oi = ((size_t)(b * T_LEN + c * 64 + 16 * w + hi * 4 + r) * H_N + h) * DV + s * 16 + li;
      out[oi] = O[r];
    }

    float ge = gam[p][63];
#pragma unroll
    for (int t = 0; t < 2; ++t) {
      f32x4 acc;
#pragma unroll
      for (int r = 0; r < 4; ++r) acc[r] = ge * S[t][r];
#pragma unroll
      for (int ks = 0; ks < 2; ++ks) {
        s16x8 fa = *(const s16x8*)(KDb[p] + ((((w + 4 * t) * 16 + li) * 128 + ks * 64 + hi * 16) ^ SWZ(li)));
        acc = __builtin_amdgcn_mfma_f32_16x16x32_bf16(fa, yfb[ks], acc, 0, 0, 0);
      }
#pragma unroll
      for (int r = 0; r < 4; ++r) S[t][r] = acc[r];
    }
    LBAR();
    WRITE_ST();
    __syncthreads();
  }

#pragma unroll
  for (int t = 0; t < 2; ++t)
#pragma unroll
    for (int r = 0; r < 4; ++r) {
      int d = (w + 4 * t) * 16 + hi * 4 + r;
      out[(size_t)(2 * T_LEN * H_N * DV) + ((size_t)bh * 128 + d) * 128 + s * 16 + li] = S[t][r];
    }
}

// ---------------- Fallback (round-5 kernel, used only if ws too small) ----
#define COLS 16
#define CHUNK 16
#define STEP_B 8192u
#define AB_B 64u
#define OSTRIDE (H_N * DV)
template <int CTRL>
__device__ __forceinline__ float dpp_add(float x) {
  int y = __builtin_amdgcn_update_dpp(0, __float_as_int(x), CTRL, 0xF, 0xF, true);
  return x + __int_as_float(y);
}
__device__ __forceinline__ float red16(float x) {
  x = dpp_add<0xB1>(x); x = dpp_add<0x4E>(x);
  x = dpp_add<0x124>(x); x = dpp_add<0x128>(x);
  return x;
}
extern "C" __global__ void __launch_bounds__(256, 1) gdn_fallback(
    const float* __restrict__ q, const float* __restrict__ k,
    const float* __restrict__ v, const float* __restrict__ al,
    const float* __restrict__ be, const float* __restrict__ S0,
    float* __restrict__ out) {
  __shared__ float kb[2][CHUNK * DK];
  __shared__ float qb[2][CHUNK * DK];
  __shared__ float vb[2][CHUNK * COLS];
  __shared__ float abuf[2][64];
  __shared__ float bbuf[2][64];
  const int bid = blockIdx.x;
  const int bh = bid & 31, g = bid >> 5;
  const int b = bh >> 4, h = bh & 15;
  const int tid = threadIdx.x;
  const int cl = tid >> 4, li = tid & 15, lane = tid & 63, wid = tid >> 6;
  const int col = g * COLS + cl, d0 = li * 8;
  const size_t bh_qk = ((size_t)b * T_LEN * H_N + h) * DK;
  const size_t bh_v = ((size_t)b * T_LEN * H_N + h) * DV;
  const size_t bh_ab = (size_t)b * T_LEN * H_N + h;
  const int fo0 = wid * 2048 + lane * 16, fo1 = fo0 + 1024;
  const char* kg0 = (const char*)(k + bh_qk) + (size_t)(fo0 >> 9) * STEP_B + (fo0 & 511);
  const char* kg1 = (const char*)(k + bh_qk) + (size_t)(fo1 >> 9) * STEP_B + (fo1 & 511);
  const char* qg0 = (const char*)(q + bh_qk) + (size_t)(fo0 >> 9) * STEP_B + (fo0 & 511);
  const char* qg1 = (const char*)(q + bh_qk) + (size_t)(fo1 >> 9) * STEP_B + (fo1 & 511);
  const int fv = lane * 16;
  const char* vg = (const char*)(v + bh_v + g * COLS) + (size_t)(fv >> 6) * STEP_B + (fv & 63);
  const int lcl = lane < 16 ? lane : 15;
  const char* ag = (const char*)(al + bh_ab) + (size_t)lcl * AB_B;
  const char* bg = (const char*)(be + bh_ab) + (size_t)lcl * AB_B;
#define STAGEF(CI, P) do { \
    const size_t off = (size_t)(CI) * (CHUNK * STEP_B); \
    const size_t offab = (size_t)(CI) * (CHUNK * AB_B); \
    GLDS16(kg0 + off, &kb[P][wid * 512]); GLDS16(kg1 + off, &kb[P][wid * 512 + 256]); \
    GLDS16(qg0 + off, &qb[P][wid * 512]); GLDS16(qg1 + off, &qb[P][wid * 512 + 256]); \
    if (wid == 0) GLDS16(vg + off, &vb[P][0]); \
    else if (wid == 1) GLDS4(ag + offab, &abuf[P][0]); \
    else if (wid == 2) GLDS4(bg + offab, &bbuf[P][0]); \
  } while (0)
  float sv[8];
  const float* s0p = S0 + ((size_t)(b * H_N + h) * DK + d0) * DV + col;
#pragma unroll
  for (int j = 0; j < 8; ++j) sv[j] = s0p[(size_t)j * DV];
  STAGEF(0, 0);
  __syncthreads();
  float* op = out + bh_v + col;
  for (int ci = 0; ci < T_LEN / CHUNK; ++ci) {
    const int p = ci & 1;
    if (ci + 1 < T_LEN / CHUNK) STAGEF(ci + 1, p ^ 1);
    const float* kc = kb[p]; const float* qc = qb[p]; const float* vc = vb[p];
    const float* ac = abuf[p]; const float* bc = bbuf[p];
#pragma unroll
    for (int j = 0; j < CHUNK; ++j) {
      f32x4 kA = *(const f32x4*)(kc + j * DK + d0);
      f32x4 kB = *(const f32x4*)(kc + j * DK + d0 + 4);
      f32x4 qA = *(const f32x4*)(qc + j * DK + d0);
      f32x4 qB = *(const f32x4*)(qc + j * DK + d0 + 4);
      float vv = vc[j * COLS + cl], aa = ac[j], bv = bc[j];
      float kk[8] = {kA[0], kA[1], kA[2], kA[3], kB[0], kB[1], kB[2], kB[3]};
      float qq[8] = {qA[0], qA[1], qA[2], qA[3], qB[0], qB[1], qB[2], qB[3]};
      float pk0 = kk[0] * sv[0], pk1 = kk[1] * sv[1];
      float pu0 = qq[0] * sv[0], pu1 = qq[1] * sv[1];
      float pg0 = kk[0] * qq[0], pg1 = kk[1] * qq[1];
#pragma unroll
      for (int m = 2; m < 8; m += 2) {
        pk0 = fmaf(kk[m], sv[m], pk0); pk1 = fmaf(kk[m + 1], sv[m + 1], pk1);
        pu0 = fmaf(qq[m], sv[m], pu0); pu1 = fmaf(qq[m + 1], sv[m + 1], pu1);
        pg0 = fmaf(kk[m], qq[m], pg0); pg1 = fmaf(kk[m + 1], qq[m + 1], pg1);
      }
      float pk = red16(pk0 + pk1), pu = red16(pu0 + pu1), pg = red16(pg0 + pg1);
      float tmp = fmaf(-(bv * aa), pk, bv * vv);
#pragma unroll
      for (int m = 0; m < 8; ++m) sv[m] = fmaf(aa, sv[m], kk[m] * tmp);
      if (li == 0) op[(size_t)(ci * CHUNK + j) * OSTRIDE] = fmaf(pg, tmp, aa * pu);
    }
    __syncthreads();
  }
  float* sf = out + (size_t)2 * T_LEN * H_N * DV + ((size_t)(b * H_N + h) * DK + d0) * DV + col;
#pragma unroll
  for (int j = 0; j < 8; ++j) sf[(size_t)j * DV] = sv[j];
}

extern "C" void kernel_launch(void* const* d_in, const int* in_sizes, int n_in,
                              void* d_out, int out_size, void* d_ws,
                              size_t ws_size, hipStream_t stream) {
  const float* q = (const float*)d_in[0];
  const float* k = (const float*)d_in[1];
  const float* v = (const float*)d_in[2];
  const float* al = (const float*)d_in[3];
  const float* be = (const float*)d_in[4];
  const float* S0 = (const float*)d_in[5];
  float* out = (float*)d_out;

  if (ws_size >= WS_NEED) {
    gdn_p1<<<dim3(2048), dim3(256), 0, stream>>>(q, k, v, al, be, (char*)d_ws);
    gdn_p2<<<dim3(256), dim3(256), 0, stream>>>(S0, out, (const char*)d_ws);
  } else {
    gdn_fallback<<<dim3(256), dim3(256), 0, stream>>>(q, k, v, al, be, S0, out);
  }
}

// Round 13
// 282.046 us; speedup vs baseline: 2.9041x; 1.0435x over previous
//
#include <hip/hip_runtime.h>

// Problem dims: B=2, T=4096, H=16, Dk=Dv=128. Chunked delta rule, L=64.
#define T_LEN 4096
#define H_N   16
#define DK    128
#define DV    128
#define LCH   64
#define NCH   64

typedef float f32x4 __attribute__((ext_vector_type(4)));
typedef short s16x8 __attribute__((ext_vector_type(8)));

// workspace layout per (head,chunk), bytes
#define OFF_U0 0        // [8 slices][64 rows][16 cols] f32 (sliced-contiguous)
#define OFF_W  32768    // 64x128 bf16, XOR-swizzled rows (negated W)
#define OFF_Q  49152    // 64x128 bf16, XOR-swizzled rows (gamma-less Q)
#define OFF_KD 65536    // 128x64 bf16, XOR-swizzled rows ([d][j] = rr_j k[j][d])
#define OFF_G  81920    // 64x64 bf16, XOR-swizzled rows
#define OFF_GM 90112    // 64 f32 (gamma_i = exp(cumsum ln a))
#define CH_B   90368ull
#define WS_NEED (2048ull * CH_B)

#define SWZ(row) (((row)&7) << 4)

// LDS strides (padded; round-12)
#define AST 68
#define RST 132

__device__ __forceinline__ unsigned short f2b(float x) {
  unsigned u = __float_as_uint(x);
  return (unsigned short)((u + 0x7FFF + ((u >> 16) & 1)) >> 16);
}

// Async global->LDS (vmcnt; drained only by full __syncthreads)
#define GLDS16(gp, lp)                                                        \
  __builtin_amdgcn_global_load_lds(                                           \
      (const __attribute__((address_space(1))) void*)(gp),                    \
      (__attribute__((address_space(3))) void*)(lp), 16, 0, 0)
#define GLDS4(gp, lp)                                                         \
  __builtin_amdgcn_global_load_lds(                                           \
      (const __attribute__((address_space(1))) void*)(gp),                    \
      (__attribute__((address_space(3))) void*)(lp), 4, 0, 0)

// LDS-only barrier: orders ds ops across waves WITHOUT draining vmcnt.
#define LBAR()                                                                \
  do {                                                                        \
    asm volatile("s_waitcnt lgkmcnt(0)" ::: "memory");                        \
    __builtin_amdgcn_s_barrier();                                             \
    __builtin_amdgcn_sched_barrier(0);                                        \
  } while (0)

// ---------------- Phase 1: per-(head,chunk) UT transform ----------------
__device__ void solve64(float* RHS, const float* A, int tid) {
#pragma unroll 1
  for (int I = 0; I < 4; ++I) {
    if (I > 0) {
      const int i2 = 16 * I + (tid >> 4), cg = tid & 15;
      float* rp = RHS + i2 * RST + cg * 8;
      f32x4 a0 = *(const f32x4*)(rp);
      f32x4 a1 = *(const f32x4*)(rp + 4);
      for (int j = 0; j < 16 * I; ++j) {
        float a = A[i2 * AST + j];
        const float* yp = RHS + j * RST + cg * 8;
        f32x4 y0 = *(const f32x4*)(yp);
        f32x4 y1 = *(const f32x4*)(yp + 4);
#pragma unroll
        for (int e = 0; e < 4; ++e) {
          a0[e] = fmaf(-a, y0[e], a0[e]);
          a1[e] = fmaf(-a, y1[e], a1[e]);
        }
      }
      *(f32x4*)(rp) = a0;
      *(f32x4*)(rp + 4) = a1;
      __syncthreads();
    }
    if (tid < 128) {
      const int col = tid;
      float y[16];
#pragma unroll
      for (int r = 0; r < 16; ++r) y[r] = RHS[(16 * I + r) * RST + col];
#pragma unroll
      for (int r = 1; r < 16; ++r) {
        float t0 = 0.f, t1 = 0.f;
#pragma unroll
        for (int j = 0; j < 15; ++j)
          if (j < r) {
            float av = A[(16 * I + r) * AST + 16 * I + j];
            if (j & 1) t1 = fmaf(av, y[j], t1);
            else       t0 = fmaf(av, y[j], t0);
          }
        y[r] -= t0 + t1;
      }
#pragma unroll
      for (int r = 0; r < 16; ++r) RHS[(16 * I + r) * RST + col] = y[r];
    }
    __syncthreads();
  }
}

extern "C" __global__ void __launch_bounds__(256) gdn_p1(
    const float* __restrict__ q, const float* __restrict__ k,
    const float* __restrict__ v, const float* __restrict__ al,
    const float* __restrict__ be, char* __restrict__ ws) {
  __shared__ __align__(16) unsigned char big[34048];
  __shared__ __align__(16) float A_s[64 * AST];
  __shared__ float g_s[64], bb_s[64], sc_s[64];
  unsigned char* Kb = big;
  unsigned char* Qb = big + 16384;
  float* RHS = (float*)big;

  const int bid = blockIdx.x;
  const int bh = bid & 31, c = bid >> 5;
  const int b = bh >> 4, h = bh & 15;
  const int tid = threadIdx.x;
  const int t0 = c * LCH;
  char* wsc = ws + (size_t)(bh * 64 + c) * CH_B;

  if (tid < 64) {
    size_t gi = (size_t)(b * T_LEN + t0 + tid) * H_N + h;
    float x = __logf(al[gi]);
    bb_s[tid] = be[gi];
#pragma unroll
    for (int d = 1; d < 64; d <<= 1) {
      float yv = __shfl_up(x, d, 64);
      if (tid >= d) x += yv;
    }
    float gam = __expf(x);
    g_s[tid] = x;
    sc_s[tid] = gam;
    *(float*)(wsc + OFF_GM + tid * 4) = gam;
  }

  for (int idx = tid; idx < 1024; idx += 256) {
    int row = idx >> 4, grp = idx & 15;
    size_t go = ((size_t)(b * T_LEN + t0 + row) * H_N + h) * DK + grp * 8;
    float4 ka = *(const float4*)(k + go);
    float4 kb2 = *(const float4*)(k + go + 4);
    float4 qa = *(const float4*)(q + go);
    float4 qb2 = *(const float4*)(q + go + 4);
    union { unsigned short u[8]; uint4 v4; } tk, tq;
    tk.u[0] = f2b(ka.x); tk.u[1] = f2b(ka.y); tk.u[2] = f2b(ka.z); tk.u[3] = f2b(ka.w);
    tk.u[4] = f2b(kb2.x); tk.u[5] = f2b(kb2.y); tk.u[6] = f2b(kb2.z); tk.u[7] = f2b(kb2.w);
    tq.u[0] = f2b(qa.x); tq.u[1] = f2b(qa.y); tq.u[2] = f2b(qa.z); tq.u[3] = f2b(qa.w);
    tq.u[4] = f2b(qb2.x); tq.u[5] = f2b(qb2.y); tq.u[6] = f2b(qb2.z); tq.u[7] = f2b(qb2.w);
    int la = (row * 256 + grp * 16) ^ SWZ(row);
    *(uint4*)(Kb + la) = tk.v4;
    *(uint4*)(Qb + la) = tq.v4;
    *(uint4*)(wsc + OFF_Q + la) = tq.v4;
  }
  __syncthreads();

  const int w = tid >> 6, l = tid & 63, li = l & 15, hi = l >> 4;
  f32x4 aK[4], aQ[4];
#pragma unroll
  for (int jt = 0; jt < 4; ++jt) { aK[jt] = (f32x4){0, 0, 0, 0}; aQ[jt] = (f32x4){0, 0, 0, 0}; }
#pragma unroll
  for (int ks = 0; ks < 4; ++ks) {
    int rowA = 16 * w + li;
    int oa = (rowA * 256 + ks * 64 + hi * 16) ^ SWZ(rowA);
    s16x8 fa = *(const s16x8*)(Kb + oa);
    s16x8 fq = *(const s16x8*)(Qb + oa);
#pragma unroll
    for (int jt = 0; jt < 4; ++jt) {
      int rowB = 16 * jt + li;
      s16x8 fb = *(const s16x8*)(Kb + ((rowB * 256 + ks * 64 + hi * 16) ^ SWZ(rowB)));
      aK[jt] = __builtin_amdgcn_mfma_f32_16x16x32_bf16(fa, fb, aK[jt], 0, 0, 0);
      aQ[jt] = __builtin_amdgcn_mfma_f32_16x16x32_bf16(fq, fb, aQ[jt], 0, 0, 0);
    }
  }
#pragma unroll
  for (int jt = 0; jt < 4; ++jt)
#pragma unroll
    for (int r = 0; r < 4; ++r) {
      int i = 16 * w + hi * 4 + r, j = 16 * jt + li;   // C layout (m89)
      float e = __expf(g_s[i] - g_s[j]);
      A_s[i * AST + j] = (j < i) ? bb_s[i] * e * aK[jt][r] : 0.f;
      *(unsigned short*)(wsc + OFF_G + ((i * 128 + j * 2) ^ SWZ(i))) =
          f2b((j <= i) ? e * aQ[jt][r] : 0.f);
    }
  __syncthreads();

  for (int idx = tid; idx < 2048; idx += 256) {
    int row = idx >> 5, c4 = idx & 31;
    float4 vv = *(const float4*)(v + ((size_t)(b * T_LEN + t0 + row) * H_N + h) * DV + c4 * 4);
    float s = bb_s[row];
    float4 o = {s * vv.x, s * vv.y, s * vv.z, s * vv.w};
    *(float4*)(RHS + row * RST + c4 * 4) = o;
  }
  __syncthreads();
  solve64(RHS, A_s, tid);
  for (int idx = tid; idx < 2048; idx += 256) {
    int row = idx >> 5, c4 = idx & 31;
    *(float4*)(wsc + OFF_U0 + (c4 >> 2) * 4096 + row * 64 + (c4 & 3) * 16) =
        *(const float4*)(RHS + row * RST + c4 * 4);
  }
  __syncthreads();

  for (int idx = tid; idx < 2048; idx += 256) {
    int row = idx >> 5, c4 = idx & 31;
    float4 kv = *(const float4*)(k + ((size_t)(b * T_LEN + t0 + row) * H_N + h) * DK + c4 * 4);
    float s = bb_s[row] * sc_s[row];
    float4 o = {s * kv.x, s * kv.y, s * kv.z, s * kv.w};
    *(float4*)(RHS + row * RST + c4 * 4) = o;
  }
  __syncthreads();
  solve64(RHS, A_s, tid);
  for (int idx = tid; idx < 1024; idx += 256) {
    int row = idx >> 4, g8 = idx & 15;
    const float* p = RHS + row * RST + g8 * 8;
    union { unsigned short u[8]; uint4 v4; } t;
#pragma unroll
    for (int e = 0; e < 8; ++e) t.u[e] = f2b(-p[e]);
    *(uint4*)(wsc + OFF_W + ((row * 256 + g8 * 16) ^ SWZ(row))) = t.v4;
  }
  __syncthreads();

  if (tid < 64) sc_s[tid] = __expf(g_s[63] - g_s[tid]);  // rr_j
  __syncthreads();
  float* Kf = (float*)big;  // 32 x 132 f32
#pragma unroll 1
  for (int p = 0; p < 2; ++p) {
    for (int idx = tid; idx < 1024; idx += 256) {
      int r = idx >> 5, c4 = idx & 31;
      float4 kv = *(const float4*)(k + ((size_t)(b * T_LEN + t0 + 32 * p + r) * H_N + h) * DK + c4 * 4);
      *(float4*)(Kf + r * 132 + c4 * 4) = kv;
    }
    __syncthreads();
#pragma unroll
    for (int m = 0; m < 16; ++m) {
      int flat = m * 256 + tid;
      int j32 = flat & 31, d = flat >> 5;
      float val = sc_s[32 * p + j32] * Kf[j32 * 132 + d];
      *(unsigned short*)(wsc + OFF_KD + ((d * 128 + (32 * p + j32) * 2) ^ SWZ(d))) = f2b(val);
    }
    __syncthreads();
  }
}

// ---------------- Phase 2: 8-wave role-split chunk recurrence ----------
// Waves 0-3 (grpA): Y = U0 + Wn*S -> Ytb; then O = Oa + G*Y -> out.
// Waves 4-7 (grpB): Oa = gamma*(Q*S) -> LDS; then S = ge*S + KD*Y (S in regs).
// 2 barriers/chunk (LBAR + syncthreads); 2 waves/SIMD TLP.
extern "C" __global__ void __launch_bounds__(512, 1) gdn_p2(
    const float* __restrict__ S0, float* __restrict__ out,
    const char* __restrict__ ws) {
  __shared__ unsigned char Wb[2][16384];
  __shared__ unsigned char Qb[2][16384];
  __shared__ unsigned char KDb[2][16384];
  __shared__ unsigned char Gb[2][8192];
  __shared__ float U0s[2][1024];
  __shared__ float gam[2][64];
  __shared__ unsigned char Stb[4096];   // S^T bf16 [16 col][128 d], swz
  __shared__ unsigned char Ytb[2048];   // Y^T bf16 [16 col][64 j], swz
  __shared__ float Oa[1024];            // 64 rows x 16 cols f32

  const int bid = blockIdx.x;
  const int bh = bid & 31, s = bid >> 5;   // siblings share (bid mod 8) -> XCD
  const int b = bh >> 4, h = bh & 15;
  const int tid = threadIdx.x;
  const int w = tid >> 6;                   // 0..7
  const int lane = tid & 63, li = lane & 15, hi = lane >> 4;
  const int wq = w & 3;                     // role-local wave index
  const bool grpA = (w < 4);
  const char* wsbase = ws + (size_t)bh * 64 * CH_B;

#define STG(CI, P)                                                            \
  do {                                                                        \
    const char* c_ = wsbase + (size_t)(CI) * CH_B;                            \
    _Pragma("unroll") for (int j_ = 0; j_ < 2; ++j_) {                        \
      GLDS16(c_ + OFF_W + j_ * 8192 + tid * 16, &Wb[P][j_ * 8192 + w * 1024]); \
      GLDS16(c_ + OFF_Q + j_ * 8192 + tid * 16, &Qb[P][j_ * 8192 + w * 1024]); \
      GLDS16(c_ + OFF_KD + j_ * 8192 + tid * 16, &KDb[P][j_ * 8192 + w * 1024]); \
    }                                                                         \
    GLDS16(c_ + OFF_G + tid * 16, &Gb[P][w * 1024]);                          \
    if (w < 4) GLDS16(c_ + OFF_U0 + s * 4096 + tid * 16,                      \
                      (unsigned char*)U0s[P] + w * 1024);                     \
    if (w == 7) GLDS4(c_ + OFF_GM + lane * 4, &gam[P][0]);                    \
  } while (0)

  // State S lives in grpB (waves 4-7): d = (wq+4t)*16 + hi*4 + r, col s*16+li
  float S[2][4];
  if (!grpA) {
#pragma unroll
    for (int t = 0; t < 2; ++t)
#pragma unroll
      for (int r = 0; r < 4; ++r) {
        int d = (wq + 4 * t) * 16 + hi * 4 + r;
        S[t][r] = S0[((size_t)bh * 128 + d) * 128 + s * 16 + li];
      }
  }
#define WRITE_ST()                                                            \
  do {                                                                        \
    _Pragma("unroll") for (int t = 0; t < 2; ++t)                             \
        _Pragma("unroll") for (int r = 0; r < 4; r += 2) {                    \
      int d = (wq + 4 * t) * 16 + hi * 4 + r;                                 \
      unsigned pk = (unsigned)f2b(S[t][r]) | ((unsigned)f2b(S[t][r + 1]) << 16); \
      *(unsigned*)(Stb + ((li * 256 + d * 2) ^ SWZ(li))) = pk;                \
    }                                                                         \
  } while (0)

  STG(0, 0);
  if (!grpA) WRITE_ST();
  __syncthreads();  // drain vmcnt (buf0) + Stb visible

#pragma unroll 1
  for (int c = 0; c < NCH; ++c) {
    const int p = c & 1;
    if (c + 1 < NCH) STG(c + 1, p ^ 1);

    // Both groups read S^T fragments (B-operand, K=128)
    s16x8 sfb[4];
#pragma unroll
    for (int ks = 0; ks < 4; ++ks)
      sfb[ks] = *(const s16x8*)(Stb + ((li * 256 + ks * 64 + hi * 16) ^ SWZ(li)));

    if (grpA) {
      // ---- Phase A (grpA): Y = U0 + Wn*S -> Ytb
      f32x4 Y;
#pragma unroll
      for (int r = 0; r < 4; ++r) Y[r] = U0s[p][(16 * wq + hi * 4 + r) * 16 + li];
#pragma unroll
      for (int ks = 0; ks < 4; ++ks) {
        s16x8 fa = *(const s16x8*)(Wb[p] + (((16 * wq + li) * 256 + ks * 64 + hi * 16) ^ SWZ(li)));
        Y = __builtin_amdgcn_mfma_f32_16x16x32_bf16(fa, sfb[ks], Y, 0, 0, 0);
      }
#pragma unroll
      for (int r = 0; r < 4; r += 2) {
        int j = 16 * wq + hi * 4 + r;
        unsigned pk = (unsigned)f2b(Y[r]) | ((unsigned)f2b(Y[r + 1]) << 16);
        *(unsigned*)(Ytb + ((li * 128 + j * 2) ^ SWZ(li))) = pk;
      }
      LBAR();
      // ---- Phase B (grpA): O = Oa + G*Y -> out
      f32x4 O;
      s16x8 yfb[2];
#pragma unroll
      for (int ks = 0; ks < 2; ++ks)
        yfb[ks] = *(const s16x8*)(Ytb + ((li * 128 + ks * 64 + hi * 16) ^ SWZ(li)));
#pragma unroll
      for (int r = 0; r < 4; ++r) O[r] = Oa[(16 * wq + hi * 4 + r) * 16 + li];
#pragma unroll
      for (int ks = 0; ks < 2; ++ks) {
        s16x8 fa = *(const s16x8*)(Gb[p] + (((16 * wq + li) * 128 + ks * 64 + hi * 16) ^ SWZ(li)));
        O = __builtin_amdgcn_mfma_f32_16x16x32_bf16(fa, yfb[ks], O, 0, 0, 0);
      }
#pragma unroll
      for (int r = 0; r < 4; ++r) {
        size_t oi = ((size_t)(b * T_LEN + c * 64 + 16 * wq + hi * 4 + r) * H_N + h) * DV + s * 16 + li;
        out[oi] = O[r];
      }
    } else {
      // ---- Phase A (grpB): Oa = gamma * (Q*S) -> LDS f32
      f32x4 Oq = {0, 0, 0, 0};
#pragma unroll
      for (int ks = 0; ks < 4; ++ks) {
        s16x8 fa = *(const s16x8*)(Qb[p] + (((16 * wq + li) * 256 + ks * 64 + hi * 16) ^ SWZ(li)));
        Oq = __builtin_amdgcn_mfma_f32_16x16x32_bf16(fa, sfb[ks], Oq, 0, 0, 0);
      }
#pragma unroll
      for (int r = 0; r < 4; ++r) {
        int row = 16 * wq + hi * 4 + r;
        Oa[row * 16 + li] = gam[p][row] * Oq[r];
      }
      LBAR();
      // ---- Phase B (grpB): S = ge*S + KD*Y; re-publish Stb
      s16x8 yfb[2];
#pragma unroll
      for (int ks = 0; ks < 2; ++ks)
        yfb[ks] = *(const s16x8*)(Ytb + ((li * 128 + ks * 64 + hi * 16) ^ SWZ(li)));
      float ge = gam[p][63];
#pragma unroll
      for (int t = 0; t < 2; ++t) {
        f32x4 acc;
#pragma unroll
        for (int r = 0; r < 4; ++r) acc[r] = ge * S[t][r];
#pragma unroll
        for (int ks = 0; ks < 2; ++ks) {
          s16x8 fa = *(const s16x8*)(KDb[p] + ((((wq + 4 * t) * 16 + li) * 128 + ks * 64 + hi * 16) ^ SWZ(li)));
          acc = __builtin_amdgcn_mfma_f32_16x16x32_bf16(fa, yfb[ks], acc, 0, 0, 0);
        }
#pragma unroll
        for (int r = 0; r < 4; ++r) S[t][r] = acc[r];
      }
      WRITE_ST();
    }
    __syncthreads();  // drain staged c+1; Stb/Ytb/Oa epoch boundary
  }

  // final state (grpB owns S)
  if (!grpA) {
#pragma unroll
    for (int t = 0; t < 2; ++t)
#pragma unroll
      for (int r = 0; r < 4; ++r) {
        int d = (wq + 4 * t) * 16 + hi * 4 + r;
        out[(size_t)(2 * T_LEN * H_N * DV) + ((size_t)bh * 128 + d) * 128 + s * 16 + li] = S[t][r];
      }
  }
}

// ---------------- Fallback (round-5 kernel, used only if ws too small) ----
#define COLS 16
#define CHUNK 16
#define STEP_B 8192u
#define AB_B 64u
#define OSTRIDE (H_N * DV)
template <int CTRL>
__device__ __forceinline__ float dpp_add(float x) {
  int y = __builtin_amdgcn_update_dpp(0, __float_as_int(x), CTRL, 0xF, 0xF, true);
  return x + __int_as_float(y);
}
__device__ __forceinline__ float red16(float x) {
  x = dpp_add<0xB1>(x); x = dpp_add<0x4E>(x);
  x = dpp_add<0x124>(x); x = dpp_add<0x128>(x);
  return x;
}
extern "C" __global__ void __launch_bounds__(256, 1) gdn_fallback(
    const float* __restrict__ q, const float* __restrict__ k,
    const float* __restrict__ v, const float* __restrict__ al,
    const float* __restrict__ be, const float* __restrict__ S0,
    float* __restrict__ out) {
  __shared__ float kb[2][CHUNK * DK];
  __shared__ float qb[2][CHUNK * DK];
  __shared__ float vb[2][CHUNK * COLS];
  __shared__ float abuf[2][64];
  __shared__ float bbuf[2][64];
  const int bid = blockIdx.x;
  const int bh = bid & 31, g = bid >> 5;
  const int b = bh >> 4, h = bh & 15;
  const int tid = threadIdx.x;
  const int cl = tid >> 4, li = tid & 15, lane = tid & 63, wid = tid >> 6;
  const int col = g * COLS + cl, d0 = li * 8;
  const size_t bh_qk = ((size_t)b * T_LEN * H_N + h) * DK;
  const size_t bh_v = ((size_t)b * T_LEN * H_N + h) * DV;
  const size_t bh_ab = (size_t)b * T_LEN * H_N + h;
  const int fo0 = wid * 2048 + lane * 16, fo1 = fo0 + 1024;
  const char* kg0 = (const char*)(k + bh_qk) + (size_t)(fo0 >> 9) * STEP_B + (fo0 & 511);
  const char* kg1 = (const char*)(k + bh_qk) + (size_t)(fo1 >> 9) * STEP_B + (fo1 & 511);
  const char* qg0 = (const char*)(q + bh_qk) + (size_t)(fo0 >> 9) * STEP_B + (fo0 & 511);
  const char* qg1 = (const char*)(q + bh_qk) + (size_t)(fo1 >> 9) * STEP_B + (fo1 & 511);
  const int fv = lane * 16;
  const char* vg = (const char*)(v + bh_v + g * COLS) + (size_t)(fv >> 6) * STEP_B + (fv & 63);
  const int lcl = lane < 16 ? lane : 15;
  const char* ag = (const char*)(al + bh_ab) + (size_t)lcl * AB_B;
  const char* bg = (const char*)(be + bh_ab) + (size_t)lcl * AB_B;
#define STAGEF(CI, P) do { \
    const size_t off = (size_t)(CI) * (CHUNK * STEP_B); \
    const size_t offab = (size_t)(CI) * (CHUNK * AB_B); \
    GLDS16(kg0 + off, &kb[P][wid * 512]); GLDS16(kg1 + off, &kb[P][wid * 512 + 256]); \
    GLDS16(qg0 + off, &qb[P][wid * 512]); GLDS16(qg1 + off, &qb[P][wid * 512 + 256]); \
    if (wid == 0) GLDS16(vg + off, &vb[P][0]); \
    else if (wid == 1) GLDS4(ag + offab, &abuf[P][0]); \
    else if (wid == 2) GLDS4(bg + offab, &bbuf[P][0]); \
  } while (0)
  float sv[8];
  const float* s0p = S0 + ((size_t)(b * H_N + h) * DK + d0) * DV + col;
#pragma unroll
  for (int j = 0; j < 8; ++j) sv[j] = s0p[(size_t)j * DV];
  STAGEF(0, 0);
  __syncthreads();
  float* op = out + bh_v + col;
  for (int ci = 0; ci < T_LEN / CHUNK; ++ci) {
    const int p = ci & 1;
    if (ci + 1 < T_LEN / CHUNK) STAGEF(ci + 1, p ^ 1);
    const float* kc = kb[p]; const float* qc = qb[p]; const float* vc = vb[p];
    const float* ac = abuf[p]; const float* bc = bbuf[p];
#pragma unroll
    for (int j = 0; j < CHUNK; ++j) {
      f32x4 kA = *(const f32x4*)(kc + j * DK + d0);
      f32x4 kB = *(const f32x4*)(kc + j * DK + d0 + 4);
      f32x4 qA = *(const f32x4*)(qc + j * DK + d0);
      f32x4 qB = *(const f32x4*)(qc + j * DK + d0 + 4);
      float vv = vc[j * COLS + cl], aa = ac[j], bv = bc[j];
      float kk[8] = {kA[0], kA[1], kA[2], kA[3], kB[0], kB[1], kB[2], kB[3]};
      float qq[8] = {qA[0], qA[1], qA[2], qA[3], qB[0], qB[1], qB[2], qB[3]};
      float pk0 = kk[0] * sv[0], pk1 = kk[1] * sv[1];
      float pu0 = qq[0] * sv[0], pu1 = qq[1] * sv[1];
      float pg0 = kk[0] * qq[0], pg1 = kk[1] * qq[1];
#pragma unroll
      for (int m = 2; m < 8; m += 2) {
        pk0 = fmaf(kk[m], sv[m], pk0); pk1 = fmaf(kk[m + 1], sv[m + 1], pk1);
        pu0 = fmaf(qq[m], sv[m], pu0); pu1 = fmaf(qq[m + 1], sv[m + 1], pu1);
        pg0 = fmaf(kk[m], qq[m], pg0); pg1 = fmaf(kk[m + 1], qq[m + 1], pg1);
      }
      float pk = red16(pk0 + pk1), pu = red16(pu0 + pu1), pg = red16(pg0 + pg1);
      float tmp = fmaf(-(bv * aa), pk, bv * vv);
#pragma unroll
      for (int m = 0; m < 8; ++m) sv[m] = fmaf(aa, sv[m], kk[m] * tmp);
      if (li == 0) op[(size_t)(ci * CHUNK + j) * OSTRIDE] = fmaf(pg, tmp, aa * pu);
    }
    __syncthreads();
  }
  float* sf = out + (size_t)2 * T_LEN * H_N * DV + ((size_t)(b * H_N + h) * DK + d0) * DV + col;
#pragma unroll
  for (int j = 0; j < 8; ++j) sf[(size_t)j * DV] = sv[j];
}

extern "C" void kernel_launch(void* const* d_in, const int* in_sizes, int n_in,
                              void* d_out, int out_size, void* d_ws,
                              size_t ws_size, hipStream_t stream) {
  const float* q = (const float*)d_in[0];
  const float* k = (const float*)d_in[1];
  const float* v = (const float*)d_in[2];
  const float* al = (const float*)d_in[3];
  const float* be = (const float*)d_in[4];
  const float* S0 = (const float*)d_in[5];
  float* out = (float*)d_out;

  if (ws_size >= WS_NEED) {
    gdn_p1<<<dim3(2048), dim3(256), 0, stream>>>(q, k, v, al, be, (char*)d_ws);
    gdn_p2<<<dim3(256), dim3(512), 0, stream>>>(S0, out, (const char*)d_ws);
  } else {
    gdn_fallback<<<dim3(256), dim3(256), 0, stream>>>(q, k, v, al, be, S0, out);
  }
}

// Round 14
// 263.872 us; speedup vs baseline: 3.1041x; 1.0689x over previous
//
#include <hip/hip_runtime.h>

// Problem dims: B=2, T=4096, H=16, Dk=Dv=128. Chunked delta rule, L=64.
#define T_LEN 4096
#define H_N   16
#define DK    128
#define DV    128
#define LCH   64
#define NCH   64

typedef float f32x4 __attribute__((ext_vector_type(4)));
typedef short s16x8 __attribute__((ext_vector_type(8)));

// workspace layout per (head,chunk), bytes
#define OFF_U0 0        // [8 slices][64 rows][16 cols] f32 (sliced-contiguous)
#define OFF_W  32768    // 64x128 bf16, XOR-swizzled rows (negated W)
#define OFF_Q  49152    // 64x128 bf16, XOR-swizzled rows (gamma-less Q)
#define OFF_KD 65536    // 128x64 bf16, XOR-swizzled rows ([d][j] = rr_j k[j][d])
#define OFF_G  81920    // 64x64 bf16, XOR-swizzled rows
#define OFF_GM 90112    // 64 f32 (gamma_i = exp(cumsum ln a))
#define CH_B   90368ull
#define WS_NEED (2048ull * CH_B)

#define SWZ(row) (((row)&7) << 4)

// LDS strides (padded; round-12)
#define AST 68
#define RST 132

__device__ __forceinline__ unsigned short f2b(float x) {
  unsigned u = __float_as_uint(x);
  return (unsigned short)((u + 0x7FFF + ((u >> 16) & 1)) >> 16);
}

// Async global->LDS (p1 + fallback only)
#define GLDS16(gp, lp)                                                        \
  __builtin_amdgcn_global_load_lds(                                           \
      (const __attribute__((address_space(1))) void*)(gp),                    \
      (__attribute__((address_space(3))) void*)(lp), 16, 0, 0)
#define GLDS4(gp, lp)                                                         \
  __builtin_amdgcn_global_load_lds(                                           \
      (const __attribute__((address_space(1))) void*)(gp),                    \
      (__attribute__((address_space(3))) void*)(lp), 4, 0, 0)

// LDS-only barrier: orders ds ops across waves WITHOUT touching vmcnt.
#define LBAR()                                                                \
  do {                                                                        \
    asm volatile("s_waitcnt lgkmcnt(0)" ::: "memory");                        \
    __builtin_amdgcn_s_barrier();                                             \
    __builtin_amdgcn_sched_barrier(0);                                        \
  } while (0)

// ---------------- Phase 1: per-(head,chunk) UT transform ----------------
__device__ void solve64(float* RHS, const float* A, int tid) {
#pragma unroll 1
  for (int I = 0; I < 4; ++I) {
    if (I > 0) {
      const int i2 = 16 * I + (tid >> 4), cg = tid & 15;
      float* rp = RHS + i2 * RST + cg * 8;
      f32x4 a0 = *(const f32x4*)(rp);
      f32x4 a1 = *(const f32x4*)(rp + 4);
      for (int j = 0; j < 16 * I; ++j) {
        float a = A[i2 * AST + j];
        const float* yp = RHS + j * RST + cg * 8;
        f32x4 y0 = *(const f32x4*)(yp);
        f32x4 y1 = *(const f32x4*)(yp + 4);
#pragma unroll
        for (int e = 0; e < 4; ++e) {
          a0[e] = fmaf(-a, y0[e], a0[e]);
          a1[e] = fmaf(-a, y1[e], a1[e]);
        }
      }
      *(f32x4*)(rp) = a0;
      *(f32x4*)(rp + 4) = a1;
      __syncthreads();
    }
    if (tid < 128) {
      const int col = tid;
      float y[16];
#pragma unroll
      for (int r = 0; r < 16; ++r) y[r] = RHS[(16 * I + r) * RST + col];
#pragma unroll
      for (int r = 1; r < 16; ++r) {
        float t0 = 0.f, t1 = 0.f;
#pragma unroll
        for (int j = 0; j < 15; ++j)
          if (j < r) {
            float av = A[(16 * I + r) * AST + 16 * I + j];
            if (j & 1) t1 = fmaf(av, y[j], t1);
            else       t0 = fmaf(av, y[j], t0);
          }
        y[r] -= t0 + t1;
      }
#pragma unroll
      for (int r = 0; r < 16; ++r) RHS[(16 * I + r) * RST + col] = y[r];
    }
    __syncthreads();
  }
}

extern "C" __global__ void __launch_bounds__(256) gdn_p1(
    const float* __restrict__ q, const float* __restrict__ k,
    const float* __restrict__ v, const float* __restrict__ al,
    const float* __restrict__ be, char* __restrict__ ws) {
  __shared__ __align__(16) unsigned char big[34048];
  __shared__ __align__(16) float A_s[64 * AST];
  __shared__ float g_s[64], bb_s[64], sc_s[64];
  unsigned char* Kb = big;
  unsigned char* Qb = big + 16384;
  float* RHS = (float*)big;

  const int bid = blockIdx.x;
  const int bh = bid & 31, c = bid >> 5;
  const int b = bh >> 4, h = bh & 15;
  const int tid = threadIdx.x;
  const int t0 = c * LCH;
  char* wsc = ws + (size_t)(bh * 64 + c) * CH_B;

  if (tid < 64) {
    size_t gi = (size_t)(b * T_LEN + t0 + tid) * H_N + h;
    float x = __logf(al[gi]);
    bb_s[tid] = be[gi];
#pragma unroll
    for (int d = 1; d < 64; d <<= 1) {
      float yv = __shfl_up(x, d, 64);
      if (tid >= d) x += yv;
    }
    float gam = __expf(x);
    g_s[tid] = x;
    sc_s[tid] = gam;
    *(float*)(wsc + OFF_GM + tid * 4) = gam;
  }

  for (int idx = tid; idx < 1024; idx += 256) {
    int row = idx >> 4, grp = idx & 15;
    size_t go = ((size_t)(b * T_LEN + t0 + row) * H_N + h) * DK + grp * 8;
    float4 ka = *(const float4*)(k + go);
    float4 kb2 = *(const float4*)(k + go + 4);
    float4 qa = *(const float4*)(q + go);
    float4 qb2 = *(const float4*)(q + go + 4);
    union { unsigned short u[8]; uint4 v4; } tk, tq;
    tk.u[0] = f2b(ka.x); tk.u[1] = f2b(ka.y); tk.u[2] = f2b(ka.z); tk.u[3] = f2b(ka.w);
    tk.u[4] = f2b(kb2.x); tk.u[5] = f2b(kb2.y); tk.u[6] = f2b(kb2.z); tk.u[7] = f2b(kb2.w);
    tq.u[0] = f2b(qa.x); tq.u[1] = f2b(qa.y); tq.u[2] = f2b(qa.z); tq.u[3] = f2b(qa.w);
    tq.u[4] = f2b(qb2.x); tq.u[5] = f2b(qb2.y); tq.u[6] = f2b(qb2.z); tq.u[7] = f2b(qb2.w);
    int la = (row * 256 + grp * 16) ^ SWZ(row);
    *(uint4*)(Kb + la) = tk.v4;
    *(uint4*)(Qb + la) = tq.v4;
    *(uint4*)(wsc + OFF_Q + la) = tq.v4;
  }
  __syncthreads();

  const int w = tid >> 6, l = tid & 63, li = l & 15, hi = l >> 4;
  f32x4 aK[4], aQ[4];
#pragma unroll
  for (int jt = 0; jt < 4; ++jt) { aK[jt] = (f32x4){0, 0, 0, 0}; aQ[jt] = (f32x4){0, 0, 0, 0}; }
#pragma unroll
  for (int ks = 0; ks < 4; ++ks) {
    int rowA = 16 * w + li;
    int oa = (rowA * 256 + ks * 64 + hi * 16) ^ SWZ(rowA);
    s16x8 fa = *(const s16x8*)(Kb + oa);
    s16x8 fq = *(const s16x8*)(Qb + oa);
#pragma unroll
    for (int jt = 0; jt < 4; ++jt) {
      int rowB = 16 * jt + li;
      s16x8 fb = *(const s16x8*)(Kb + ((rowB * 256 + ks * 64 + hi * 16) ^ SWZ(rowB)));
      aK[jt] = __builtin_amdgcn_mfma_f32_16x16x32_bf16(fa, fb, aK[jt], 0, 0, 0);
      aQ[jt] = __builtin_amdgcn_mfma_f32_16x16x32_bf16(fq, fb, aQ[jt], 0, 0, 0);
    }
  }
#pragma unroll
  for (int jt = 0; jt < 4; ++jt)
#pragma unroll
    for (int r = 0; r < 4; ++r) {
      int i = 16 * w + hi * 4 + r, j = 16 * jt + li;   // C layout (m89)
      float e = __expf(g_s[i] - g_s[j]);
      A_s[i * AST + j] = (j < i) ? bb_s[i] * e * aK[jt][r] : 0.f;
      *(unsigned short*)(wsc + OFF_G + ((i * 128 + j * 2) ^ SWZ(i))) =
          f2b((j <= i) ? e * aQ[jt][r] : 0.f);
    }
  __syncthreads();

  for (int idx = tid; idx < 2048; idx += 256) {
    int row = idx >> 5, c4 = idx & 31;
    float4 vv = *(const float4*)(v + ((size_t)(b * T_LEN + t0 + row) * H_N + h) * DV + c4 * 4);
    float s = bb_s[row];
    float4 o = {s * vv.x, s * vv.y, s * vv.z, s * vv.w};
    *(float4*)(RHS + row * RST + c4 * 4) = o;
  }
  __syncthreads();
  solve64(RHS, A_s, tid);
  for (int idx = tid; idx < 2048; idx += 256) {
    int row = idx >> 5, c4 = idx & 31;
    *(float4*)(wsc + OFF_U0 + (c4 >> 2) * 4096 + row * 64 + (c4 & 3) * 16) =
        *(const float4*)(RHS + row * RST + c4 * 4);
  }
  __syncthreads();

  for (int idx = tid; idx < 2048; idx += 256) {
    int row = idx >> 5, c4 = idx & 31;
    float4 kv = *(const float4*)(k + ((size_t)(b * T_LEN + t0 + row) * H_N + h) * DK + c4 * 4);
    float s = bb_s[row] * sc_s[row];
    float4 o = {s * kv.x, s * kv.y, s * kv.z, s * kv.w};
    *(float4*)(RHS + row * RST + c4 * 4) = o;
  }
  __syncthreads();
  solve64(RHS, A_s, tid);
  for (int idx = tid; idx < 1024; idx += 256) {
    int row = idx >> 4, g8 = idx & 15;
    const float* p = RHS + row * RST + g8 * 8;
    union { unsigned short u[8]; uint4 v4; } t;
#pragma unroll
    for (int e = 0; e < 8; ++e) t.u[e] = f2b(-p[e]);
    *(uint4*)(wsc + OFF_W + ((row * 256 + g8 * 16) ^ SWZ(row))) = t.v4;
  }
  __syncthreads();

  if (tid < 64) sc_s[tid] = __expf(g_s[63] - g_s[tid]);  // rr_j
  __syncthreads();
  float* Kf = (float*)big;  // 32 x 132 f32
#pragma unroll 1
  for (int p = 0; p < 2; ++p) {
    for (int idx = tid; idx < 1024; idx += 256) {
      int r = idx >> 5, c4 = idx & 31;
      float4 kv = *(const float4*)(k + ((size_t)(b * T_LEN + t0 + 32 * p + r) * H_N + h) * DK + c4 * 4);
      *(float4*)(Kf + r * 132 + c4 * 4) = kv;
    }
    __syncthreads();
#pragma unroll
    for (int m = 0; m < 16; ++m) {
      int flat = m * 256 + tid;
      int j32 = flat & 31, d = flat >> 5;
      float val = sc_s[32 * p + j32] * Kf[j32 * 132 + d];
      *(unsigned short*)(wsc + OFF_KD + ((d * 128 + (32 * p + j32) * 2) ^ SWZ(d))) = f2b(val);
    }
    __syncthreads();
  }
}

// ---------------- Phase 2: 8-wave role-split, DIRECT register loads ------
// No global_load_lds: fragments load straight from ws (L2) into VGPRs; the
// compiler attaches per-use vmcnt waits, so no barrier ever drains vmcnt.
// LDS holds only Stb/Ytb/Oa (~7KB). 2 LDS-only barriers per chunk.
extern "C" __global__ void __launch_bounds__(512, 1) gdn_p2(
    const float* __restrict__ S0, float* __restrict__ out,
    const char* __restrict__ ws) {
  __shared__ unsigned char Stb[4096];   // S^T bf16 [16 col][128 d], swz
  __shared__ unsigned char Ytb[2048];   // Y^T bf16 [16 col][64 j], swz
  __shared__ float Oa[1024];            // 64 rows x 16 cols f32

  const int bid = blockIdx.x;
  const int bh = bid & 31, s = bid >> 5;   // siblings share (bid mod 8) -> XCD
  const int b = bh >> 4, h = bh & 15;
  const int tid = threadIdx.x;
  const int w = tid >> 6;                   // 0..7
  const int lane = tid & 63, li = lane & 15, hi = lane >> 4;
  const int wq = w & 3;
  const bool grpA = (w < 4);
  const char* wsbase = ws + (size_t)bh * 64 * CH_B;

  float S[2][4];
  if (!grpA) {
#pragma unroll
    for (int t = 0; t < 2; ++t)
#pragma unroll
      for (int r = 0; r < 4; ++r) {
        int d = (wq + 4 * t) * 16 + hi * 4 + r;
        S[t][r] = S0[((size_t)bh * 128 + d) * 128 + s * 16 + li];
      }
  }
#define WRITE_ST()                                                            \
  do {                                                                        \
    _Pragma("unroll") for (int t = 0; t < 2; ++t)                             \
        _Pragma("unroll") for (int r = 0; r < 4; r += 2) {                    \
      int d = (wq + 4 * t) * 16 + hi * 4 + r;                                 \
      unsigned pk = (unsigned)f2b(S[t][r]) | ((unsigned)f2b(S[t][r + 1]) << 16); \
      *(unsigned*)(Stb + ((li * 256 + d * 2) ^ SWZ(li))) = pk;                \
    }                                                                         \
  } while (0)

  if (!grpA) WRITE_ST();
  LBAR();  // Stb visible

#pragma unroll 1
  for (int c = 0; c < NCH; ++c) {
    const char* c_ = wsbase + (size_t)c * CH_B;

    // ---- early-issue direct loads for this chunk (land in VGPRs; vmcnt
    // waits attach to first use, hiding L2 latency under compute)
    s16x8 fA[4], fB[2], fB2[2];
    f32x4 u0;
    float gr[4], ge = 0.f;
    if (grpA) {
#pragma unroll
      for (int ks = 0; ks < 4; ++ks)
        fA[ks] = *(const s16x8*)(c_ + OFF_W +
                    (((16 * wq + li) * 256 + ks * 64 + hi * 16) ^ SWZ(li)));
#pragma unroll
      for (int ks = 0; ks < 2; ++ks)
        fB[ks] = *(const s16x8*)(c_ + OFF_G +
                    (((16 * wq + li) * 128 + ks * 64 + hi * 16) ^ SWZ(li)));
#pragma unroll
      for (int r = 0; r < 4; ++r)
        u0[r] = *(const float*)(c_ + OFF_U0 + s * 4096 +
                                ((16 * wq + hi * 4 + r) * 16 + li) * 4);
    } else {
#pragma unroll
      for (int ks = 0; ks < 4; ++ks)
        fA[ks] = *(const s16x8*)(c_ + OFF_Q +
                    (((16 * wq + li) * 256 + ks * 64 + hi * 16) ^ SWZ(li)));
#pragma unroll
      for (int t = 0; t < 2; ++t)
#pragma unroll
        for (int ks = 0; ks < 2; ++ks)
          ((t == 0) ? fB : fB2)[ks] = *(const s16x8*)(c_ + OFF_KD +
              ((((wq + 4 * t) * 16 + li) * 128 + ks * 64 + hi * 16) ^ SWZ(li)));
#pragma unroll
      for (int r = 0; r < 4; ++r)
        gr[r] = *(const float*)(c_ + OFF_GM + (16 * wq + hi * 4 + r) * 4);
      ge = *(const float*)(c_ + OFF_GM + 63 * 4);
    }

    // ---- S^T fragments (both groups)
    s16x8 sfb[4];
#pragma unroll
    for (int ks = 0; ks < 4; ++ks)
      sfb[ks] = *(const s16x8*)(Stb + ((li * 256 + ks * 64 + hi * 16) ^ SWZ(li)));

    if (grpA) {
      // Phase A: Y = U0 + Wn*S -> Ytb
      f32x4 Y = u0;
#pragma unroll
      for (int ks = 0; ks < 4; ++ks)
        Y = __builtin_amdgcn_mfma_f32_16x16x32_bf16(fA[ks], sfb[ks], Y, 0, 0, 0);
#pragma unroll
      for (int r = 0; r < 4; r += 2) {
        int j = 16 * wq + hi * 4 + r;
        unsigned pk = (unsigned)f2b(Y[r]) | ((unsigned)f2b(Y[r + 1]) << 16);
        *(unsigned*)(Ytb + ((li * 128 + j * 2) ^ SWZ(li))) = pk;
      }
      LBAR();
      // Phase B: O = Oa + G*Y -> out
      s16x8 yfb[2];
#pragma unroll
      for (int ks = 0; ks < 2; ++ks)
        yfb[ks] = *(const s16x8*)(Ytb + ((li * 128 + ks * 64 + hi * 16) ^ SWZ(li)));
      f32x4 O;
#pragma unroll
      for (int r = 0; r < 4; ++r) O[r] = Oa[(16 * wq + hi * 4 + r) * 16 + li];
#pragma unroll
      for (int ks = 0; ks < 2; ++ks)
        O = __builtin_amdgcn_mfma_f32_16x16x32_bf16(fB[ks], yfb[ks], O, 0, 0, 0);
#pragma unroll
      for (int r = 0; r < 4; ++r) {
        size_t oi = ((size_t)(b * T_LEN + c * 64 + 16 * wq + hi * 4 + r) * H_N + h) * DV + s * 16 + li;
        out[oi] = O[r];
      }
    } else {
      // Phase A: Oa = gamma * (Q*S)
      f32x4 Oq = {0, 0, 0, 0};
#pragma unroll
      for (int ks = 0; ks < 4; ++ks)
        Oq = __builtin_amdgcn_mfma_f32_16x16x32_bf16(fA[ks], sfb[ks], Oq, 0, 0, 0);
#pragma unroll
      for (int r = 0; r < 4; ++r) {
        int row = 16 * wq + hi * 4 + r;
        Oa[row * 16 + li] = gr[r] * Oq[r];
      }
      LBAR();
      // Phase B: S = ge*S + KD*Y; republish Stb
      s16x8 yfb[2];
#pragma unroll
      for (int ks = 0; ks < 2; ++ks)
        yfb[ks] = *(const s16x8*)(Ytb + ((li * 128 + ks * 64 + hi * 16) ^ SWZ(li)));
      {
        f32x4 acc;
#pragma unroll
        for (int r = 0; r < 4; ++r) acc[r] = ge * S[0][r];
#pragma unroll
        for (int ks = 0; ks < 2; ++ks)
          acc = __builtin_amdgcn_mfma_f32_16x16x32_bf16(fB[ks], yfb[ks], acc, 0, 0, 0);
#pragma unroll
        for (int r = 0; r < 4; ++r) S[0][r] = acc[r];
      }
      {
        f32x4 acc;
#pragma unroll
        for (int r = 0; r < 4; ++r) acc[r] = ge * S[1][r];
#pragma unroll
        for (int ks = 0; ks < 2; ++ks)
          acc = __builtin_amdgcn_mfma_f32_16x16x32_bf16(fB2[ks], yfb[ks], acc, 0, 0, 0);
#pragma unroll
        for (int r = 0; r < 4; ++r) S[1][r] = acc[r];
      }
      WRITE_ST();
    }
    LBAR();  // end-of-chunk epoch: Stb/Ytb/Oa
  }

  if (!grpA) {
#pragma unroll
    for (int t = 0; t < 2; ++t)
#pragma unroll
      for (int r = 0; r < 4; ++r) {
        int d = (wq + 4 * t) * 16 + hi * 4 + r;
        out[(size_t)(2 * T_LEN * H_N * DV) + ((size_t)bh * 128 + d) * 128 + s * 16 + li] = S[t][r];
      }
  }
}

// ---------------- Fallback (round-5 kernel, used only if ws too small) ----
#define COLS 16
#define CHUNK 16
#define STEP_B 8192u
#define AB_B 64u
#define OSTRIDE (H_N * DV)
template <int CTRL>
__device__ __forceinline__ float dpp_add(float x) {
  int y = __builtin_amdgcn_update_dpp(0, __float_as_int(x), CTRL, 0xF, 0xF, true);
  return x + __int_as_float(y);
}
__device__ __forceinline__ float red16(float x) {
  x = dpp_add<0xB1>(x); x = dpp_add<0x4E>(x);
  x = dpp_add<0x124>(x); x = dpp_add<0x128>(x);
  return x;
}
extern "C" __global__ void __launch_bounds__(256, 1) gdn_fallback(
    const float* __restrict__ q, const float* __restrict__ k,
    const float* __restrict__ v, const float* __restrict__ al,
    const float* __restrict__ be, const float* __restrict__ S0,
    float* __restrict__ out) {
  __shared__ float kb[2][CHUNK * DK];
  __shared__ float qb[2][CHUNK * DK];
  __shared__ float vb[2][CHUNK * COLS];
  __shared__ float abuf[2][64];
  __shared__ float bbuf[2][64];
  const int bid = blockIdx.x;
  const int bh = bid & 31, g = bid >> 5;
  const int b = bh >> 4, h = bh & 15;
  const int tid = threadIdx.x;
  const int cl = tid >> 4, li = tid & 15, lane = tid & 63, wid = tid >> 6;
  const int col = g * COLS + cl, d0 = li * 8;
  const size_t bh_qk = ((size_t)b * T_LEN * H_N + h) * DK;
  const size_t bh_v = ((size_t)b * T_LEN * H_N + h) * DV;
  const size_t bh_ab = (size_t)b * T_LEN * H_N + h;
  const int fo0 = wid * 2048 + lane * 16, fo1 = fo0 + 1024;
  const char* kg0 = (const char*)(k + bh_qk) + (size_t)(fo0 >> 9) * STEP_B + (fo0 & 511);
  const char* kg1 = (const char*)(k + bh_qk) + (size_t)(fo1 >> 9) * STEP_B + (fo1 & 511);
  const char* qg0 = (const char*)(q + bh_qk) + (size_t)(fo0 >> 9) * STEP_B + (fo0 & 511);
  const char* qg1 = (const char*)(q + bh_qk) + (size_t)(fo1 >> 9) * STEP_B + (fo1 & 511);
  const int fv = lane * 16;
  const char* vg = (const char*)(v + bh_v + g * COLS) + (size_t)(fv >> 6) * STEP_B + (fv & 63);
  const int lcl = lane < 16 ? lane : 15;
  const char* ag = (const char*)(al + bh_ab) + (size_t)lcl * AB_B;
  const char* bg = (const char*)(be + bh_ab) + (size_t)lcl * AB_B;
#define STAGEF(CI, P) do { \
    const size_t off = (size_t)(CI) * (CHUNK * STEP_B); \
    const size_t offab = (size_t)(CI) * (CHUNK * AB_B); \
    GLDS16(kg0 + off, &kb[P][wid * 512]); GLDS16(kg1 + off, &kb[P][wid * 512 + 256]); \
    GLDS16(qg0 + off, &qb[P][wid * 512]); GLDS16(qg1 + off, &qb[P][wid * 512 + 256]); \
    if (wid == 0) GLDS16(vg + off, &vb[P][0]); \
    else if (wid == 1) GLDS4(ag + offab, &abuf[P][0]); \
    else if (wid == 2) GLDS4(bg + offab, &bbuf[P][0]); \
  } while (0)
  float sv[8];
  const float* s0p = S0 + ((size_t)(b * H_N + h) * DK + d0) * DV + col;
#pragma unroll
  for (int j = 0; j < 8; ++j) sv[j] = s0p[(size_t)j * DV];
  STAGEF(0, 0);
  __syncthreads();
  float* op = out + bh_v + col;
  for (int ci = 0; ci < T_LEN / CHUNK; ++ci) {
    const int p = ci & 1;
    if (ci + 1 < T_LEN / CHUNK) STAGEF(ci + 1, p ^ 1);
    const float* kc = kb[p]; const float* qc = qb[p]; const float* vc = vb[p];
    const float* ac = abuf[p]; const float* bc = bbuf[p];
#pragma unroll
    for (int j = 0; j < CHUNK; ++j) {
      f32x4 kA = *(const f32x4*)(kc + j * DK + d0);
      f32x4 kB = *(const f32x4*)(kc + j * DK + d0 + 4);
      f32x4 qA = *(const f32x4*)(qc + j * DK + d0);
      f32x4 qB = *(const f32x4*)(qc + j * DK + d0 + 4);
      float vv = vc[j * COLS + cl], aa = ac[j], bv = bc[j];
      float kk[8] = {kA[0], kA[1], kA[2], kA[3], kB[0], kB[1], kB[2], kB[3]};
      float qq[8] = {qA[0], qA[1], qA[2], qA[3], qB[0], qB[1], qB[2], qB[3]};
      float pk0 = kk[0] * sv[0], pk1 = kk[1] * sv[1];
      float pu0 = qq[0] * sv[0], pu1 = qq[1] * sv[1];
      float pg0 = kk[0] * qq[0], pg1 = kk[1] * qq[1];
#pragma unroll
      for (int m = 2; m < 8; m += 2) {
        pk0 = fmaf(kk[m], sv[m], pk0); pk1 = fmaf(kk[m + 1], sv[m + 1], pk1);
        pu0 = fmaf(qq[m], sv[m], pu0); pu1 = fmaf(qq[m + 1], sv[m + 1], pu1);
        pg0 = fmaf(kk[m], qq[m], pg0); pg1 = fmaf(kk[m + 1], qq[m + 1], pg1);
      }
      float pk = red16(pk0 + pk1), pu = red16(pu0 + pu1), pg = red16(pg0 + pg1);
      float tmp = fmaf(-(bv * aa), pk, bv * vv);
#pragma unroll
      for (int m = 0; m < 8; ++m) sv[m] = fmaf(aa, sv[m], kk[m] * tmp);
      if (li == 0) op[(size_t)(ci * CHUNK + j) * OSTRIDE] = fmaf(pg, tmp, aa * pu);
    }
    __syncthreads();
  }
  float* sf = out + (size_t)2 * T_LEN * H_N * DV + ((size_t)(b * H_N + h) * DK + d0) * DV + col;
#pragma unroll
  for (int j = 0; j < 8; ++j) sf[(size_t)j * DV] = sv[j];
}

extern "C" void kernel_launch(void* const* d_in, const int* in_sizes, int n_in,
                              void* d_out, int out_size, void* d_ws,
                              size_t ws_size, hipStream_t stream) {
  const float* q = (const float*)d_in[0];
  const float* k = (const float*)d_in[1];
  const float* v = (const float*)d_in[2];
  const float* al = (const float*)d_in[3];
  const float* be = (const float*)d_in[4];
  const float* S0 = (const float*)d_in[5];
  float* out = (float*)d_out;

  if (ws_size >= WS_NEED) {
    gdn_p1<<<dim3(2048), dim3(256), 0, stream>>>(q, k, v, al, be, (char*)d_ws);
    gdn_p2<<<dim3(256), dim3(512), 0, stream>>>(S0, out, (const char*)d_ws);
  } else {
    gdn_fallback<<<dim3(256), dim3(256), 0, stream>>>(q, k, v, al, be, S0, out);
  }
}

// Round 15
// 256.437 us; speedup vs baseline: 3.1941x; 1.0290x over previous
//
#include <hip/hip_runtime.h>

// Problem dims: B=2, T=4096, H=16, Dk=Dv=128. Chunked delta rule, L=64.
#define T_LEN 4096
#define H_N   16
#define DK    128
#define DV    128
#define LCH   64
#define NCH   64

typedef float f32x4 __attribute__((ext_vector_type(4)));
typedef short s16x8 __attribute__((ext_vector_type(8)));

// workspace layout per (head,chunk), bytes
#define OFF_U0 0        // [8 slices][64 rows][16 cols] f32 (sliced-contiguous)
#define OFF_W  32768    // 64x128 bf16, XOR-swizzled rows (negated W)
#define OFF_Q  49152    // 64x128 bf16, XOR-swizzled rows (gamma-less Q)
#define OFF_KD 65536    // 128x64 bf16, XOR-swizzled rows ([d][j] = rr_j k[j][d])
#define OFF_G  81920    // 64x64 bf16, XOR-swizzled rows
#define OFF_GM 90112    // 64 f32 (gamma_i = exp(cumsum ln a))
#define CH_B   90368ull
#define WS_NEED (2048ull * CH_B)

#define SWZ(row) (((row)&7) << 4)

// LDS strides (padded; round-12)
#define AST 68
#define RST 132

__device__ __forceinline__ unsigned short f2b(float x) {
  unsigned u = __float_as_uint(x);
  return (unsigned short)((u + 0x7FFF + ((u >> 16) & 1)) >> 16);
}

// Async global->LDS (p1 + fallback only)
#define GLDS16(gp, lp)                                                        \
  __builtin_amdgcn_global_load_lds(                                           \
      (const __attribute__((address_space(1))) void*)(gp),                    \
      (__attribute__((address_space(3))) void*)(lp), 16, 0, 0)
#define GLDS4(gp, lp)                                                         \
  __builtin_amdgcn_global_load_lds(                                           \
      (const __attribute__((address_space(1))) void*)(gp),                    \
      (__attribute__((address_space(3))) void*)(lp), 4, 0, 0)

// LDS-only barrier: orders ds ops across waves WITHOUT touching vmcnt.
#define LBAR()                                                                \
  do {                                                                        \
    asm volatile("s_waitcnt lgkmcnt(0)" ::: "memory");                        \
    __builtin_amdgcn_s_barrier();                                             \
    __builtin_amdgcn_sched_barrier(0);                                        \
  } while (0)

// ---------------- Phase 1: per-(head,chunk) UT transform ----------------
// Off-diag (round-15): 128 threads x (4 rows x 4 cols) -> Y[j] slice read
// ONCE per 4 dst rows (was once per row) -> off-diag LDS traffic / 4.
__device__ void solve64(float* RHS, const float* A, int tid) {
#pragma unroll 1
  for (int I = 0; I < 4; ++I) {
    if (I > 0) {
      if (tid < 128) {
        const int rg = tid >> 5;          // 0..3 -> 4 dst rows each
        const int r0 = 16 * I + rg * 4;
        const int cs = (tid & 31) * 4;    // 4-col slice
        f32x4 acc0 = *(const f32x4*)(RHS + (r0 + 0) * RST + cs);
        f32x4 acc1 = *(const f32x4*)(RHS + (r0 + 1) * RST + cs);
        f32x4 acc2 = *(const f32x4*)(RHS + (r0 + 2) * RST + cs);
        f32x4 acc3 = *(const f32x4*)(RHS + (r0 + 3) * RST + cs);
        for (int j = 0; j < 16 * I; ++j) {
          f32x4 yv = *(const f32x4*)(RHS + j * RST + cs);
          float a0 = A[(r0 + 0) * AST + j];   // banks differ by 4/row: free
          float a1 = A[(r0 + 1) * AST + j];
          float a2 = A[(r0 + 2) * AST + j];
          float a3 = A[(r0 + 3) * AST + j];
#pragma unroll
          for (int e = 0; e < 4; ++e) {
            acc0[e] = fmaf(-a0, yv[e], acc0[e]);
            acc1[e] = fmaf(-a1, yv[e], acc1[e]);
            acc2[e] = fmaf(-a2, yv[e], acc2[e]);
            acc3[e] = fmaf(-a3, yv[e], acc3[e]);
          }
        }
        *(f32x4*)(RHS + (r0 + 0) * RST + cs) = acc0;
        *(f32x4*)(RHS + (r0 + 1) * RST + cs) = acc1;
        *(f32x4*)(RHS + (r0 + 2) * RST + cs) = acc2;
        *(f32x4*)(RHS + (r0 + 3) * RST + cs) = acc3;
      }
      __syncthreads();
    }
    // diagonal 16x16 block, serial rows, 128 threads (1 col each)
    if (tid < 128) {
      const int col = tid;
      float y[16];
#pragma unroll
      for (int r = 0; r < 16; ++r) y[r] = RHS[(16 * I + r) * RST + col];
#pragma unroll
      for (int r = 1; r < 16; ++r) {
        float t0 = 0.f, t1 = 0.f;
#pragma unroll
        for (int j = 0; j < 15; ++j)
          if (j < r) {
            float av = A[(16 * I + r) * AST + 16 * I + j];
            if (j & 1) t1 = fmaf(av, y[j], t1);
            else       t0 = fmaf(av, y[j], t0);
          }
        y[r] -= t0 + t1;
      }
#pragma unroll
      for (int r = 0; r < 16; ++r) RHS[(16 * I + r) * RST + col] = y[r];
    }
    __syncthreads();
  }
}

extern "C" __global__ void __launch_bounds__(256) gdn_p1(
    const float* __restrict__ q, const float* __restrict__ k,
    const float* __restrict__ v, const float* __restrict__ al,
    const float* __restrict__ be, char* __restrict__ ws) {
  __shared__ __align__(16) unsigned char big[34048];
  __shared__ __align__(16) float A_s[64 * AST];
  __shared__ float g_s[64], bb_s[64], sc_s[64];
  unsigned char* Kb = big;
  unsigned char* Qb = big + 16384;
  float* RHS = (float*)big;

  const int bid = blockIdx.x;
  const int bh = bid & 31, c = bid >> 5;
  const int b = bh >> 4, h = bh & 15;
  const int tid = threadIdx.x;
  const int t0 = c * LCH;
  char* wsc = ws + (size_t)(bh * 64 + c) * CH_B;

  if (tid < 64) {
    size_t gi = (size_t)(b * T_LEN + t0 + tid) * H_N + h;
    float x = __logf(al[gi]);
    bb_s[tid] = be[gi];
#pragma unroll
    for (int d = 1; d < 64; d <<= 1) {
      float yv = __shfl_up(x, d, 64);
      if (tid >= d) x += yv;
    }
    float gam = __expf(x);
    g_s[tid] = x;
    sc_s[tid] = gam;
    *(float*)(wsc + OFF_GM + tid * 4) = gam;
  }

  for (int idx = tid; idx < 1024; idx += 256) {
    int row = idx >> 4, grp = idx & 15;
    size_t go = ((size_t)(b * T_LEN + t0 + row) * H_N + h) * DK + grp * 8;
    float4 ka = *(const float4*)(k + go);
    float4 kb2 = *(const float4*)(k + go + 4);
    float4 qa = *(const float4*)(q + go);
    float4 qb2 = *(const float4*)(q + go + 4);
    union { unsigned short u[8]; uint4 v4; } tk, tq;
    tk.u[0] = f2b(ka.x); tk.u[1] = f2b(ka.y); tk.u[2] = f2b(ka.z); tk.u[3] = f2b(ka.w);
    tk.u[4] = f2b(kb2.x); tk.u[5] = f2b(kb2.y); tk.u[6] = f2b(kb2.z); tk.u[7] = f2b(kb2.w);
    tq.u[0] = f2b(qa.x); tq.u[1] = f2b(qa.y); tq.u[2] = f2b(qa.z); tq.u[3] = f2b(qa.w);
    tq.u[4] = f2b(qb2.x); tq.u[5] = f2b(qb2.y); tq.u[6] = f2b(qb2.z); tq.u[7] = f2b(qb2.w);
    int la = (row * 256 + grp * 16) ^ SWZ(row);
    *(uint4*)(Kb + la) = tk.v4;
    *(uint4*)(Qb + la) = tq.v4;
    *(uint4*)(wsc + OFF_Q + la) = tq.v4;
  }
  __syncthreads();

  const int w = tid >> 6, l = tid & 63, li = l & 15, hi = l >> 4;
  f32x4 aK[4], aQ[4];
#pragma unroll
  for (int jt = 0; jt < 4; ++jt) { aK[jt] = (f32x4){0, 0, 0, 0}; aQ[jt] = (f32x4){0, 0, 0, 0}; }
#pragma unroll
  for (int ks = 0; ks < 4; ++ks) {
    int rowA = 16 * w + li;
    int oa = (rowA * 256 + ks * 64 + hi * 16) ^ SWZ(rowA);
    s16x8 fa = *(const s16x8*)(Kb + oa);
    s16x8 fq = *(const s16x8*)(Qb + oa);
#pragma unroll
    for (int jt = 0; jt < 4; ++jt) {
      int rowB = 16 * jt + li;
      s16x8 fb = *(const s16x8*)(Kb + ((rowB * 256 + ks * 64 + hi * 16) ^ SWZ(rowB)));
      aK[jt] = __builtin_amdgcn_mfma_f32_16x16x32_bf16(fa, fb, aK[jt], 0, 0, 0);
      aQ[jt] = __builtin_amdgcn_mfma_f32_16x16x32_bf16(fq, fb, aQ[jt], 0, 0, 0);
    }
  }
#pragma unroll
  for (int jt = 0; jt < 4; ++jt)
#pragma unroll
    for (int r = 0; r < 4; ++r) {
      int i = 16 * w + hi * 4 + r, j = 16 * jt + li;   // C layout (m89)
      float e = __expf(g_s[i] - g_s[j]);
      A_s[i * AST + j] = (j < i) ? bb_s[i] * e * aK[jt][r] : 0.f;
      *(unsigned short*)(wsc + OFF_G + ((i * 128 + j * 2) ^ SWZ(i))) =
          f2b((j <= i) ? e * aQ[jt][r] : 0.f);
    }
  __syncthreads();

  for (int idx = tid; idx < 2048; idx += 256) {
    int row = idx >> 5, c4 = idx & 31;
    float4 vv = *(const float4*)(v + ((size_t)(b * T_LEN + t0 + row) * H_N + h) * DV + c4 * 4);
    float s = bb_s[row];
    float4 o = {s * vv.x, s * vv.y, s * vv.z, s * vv.w};
    *(float4*)(RHS + row * RST + c4 * 4) = o;
  }
  __syncthreads();
  solve64(RHS, A_s, tid);
  for (int idx = tid; idx < 2048; idx += 256) {
    int row = idx >> 5, c4 = idx & 31;
    *(float4*)(wsc + OFF_U0 + (c4 >> 2) * 4096 + row * 64 + (c4 & 3) * 16) =
        *(const float4*)(RHS + row * RST + c4 * 4);
  }
  __syncthreads();

  for (int idx = tid; idx < 2048; idx += 256) {
    int row = idx >> 5, c4 = idx & 31;
    float4 kv = *(const float4*)(k + ((size_t)(b * T_LEN + t0 + row) * H_N + h) * DK + c4 * 4);
    float s = bb_s[row] * sc_s[row];
    float4 o = {s * kv.x, s * kv.y, s * kv.z, s * kv.w};
    *(float4*)(RHS + row * RST + c4 * 4) = o;
  }
  __syncthreads();
  solve64(RHS, A_s, tid);
  for (int idx = tid; idx < 1024; idx += 256) {
    int row = idx >> 4, g8 = idx & 15;
    const float* p = RHS + row * RST + g8 * 8;
    union { unsigned short u[8]; uint4 v4; } t;
#pragma unroll
    for (int e = 0; e < 8; ++e) t.u[e] = f2b(-p[e]);
    *(uint4*)(wsc + OFF_W + ((row * 256 + g8 * 16) ^ SWZ(row))) = t.v4;
  }
  __syncthreads();

  if (tid < 64) sc_s[tid] = __expf(g_s[63] - g_s[tid]);  // rr_j
  __syncthreads();
  float* Kf = (float*)big;  // 32 x 132 f32
#pragma unroll 1
  for (int p = 0; p < 2; ++p) {
    for (int idx = tid; idx < 1024; idx += 256) {
      int r = idx >> 5, c4 = idx & 31;
      float4 kv = *(const float4*)(k + ((size_t)(b * T_LEN + t0 + 32 * p + r) * H_N + h) * DK + c4 * 4);
      *(float4*)(Kf + r * 132 + c4 * 4) = kv;
    }
    __syncthreads();
#pragma unroll
    for (int m = 0; m < 16; ++m) {
      int flat = m * 256 + tid;
      int j32 = flat & 31, d = flat >> 5;
      float val = sc_s[32 * p + j32] * Kf[j32 * 132 + d];
      *(unsigned short*)(wsc + OFF_KD + ((d * 128 + (32 * p + j32) * 2) ^ SWZ(d))) = f2b(val);
    }
    __syncthreads();
  }
}

// ---------------- Phase 2: role-split + 2-deep chunk pipeline ------------
// Direct register loads from ws; chunk c+1's loads issue at the TOP of
// chunk c's body (named double buffers, no runtime indexing) so a full
// chunk of compute (~2k cyc) covers L2 latency.
#define DECLBUF(S)                                                            \
  s16x8 fA0##S, fA1##S, fA2##S, fA3##S, fB0##S, fB1##S, fC0##S, fC1##S;       \
  f32x4 u0##S;                                                                \
  float gr0##S, gr1##S, gr2##S, gr3##S, ge##S;

#define LOADC(S, CI)                                                          \
  do {                                                                        \
    const char* c_ = wsbase + (size_t)(CI) * CH_B;                            \
    if (grpA) {                                                               \
      fA0##S = *(const s16x8*)(c_ + OFF_W + (((16 * wq + li) * 256 + 0 * 64 + hi * 16) ^ SWZ(li))); \
      fA1##S = *(const s16x8*)(c_ + OFF_W + (((16 * wq + li) * 256 + 1 * 64 + hi * 16) ^ SWZ(li))); \
      fA2##S = *(const s16x8*)(c_ + OFF_W + (((16 * wq + li) * 256 + 2 * 64 + hi * 16) ^ SWZ(li))); \
      fA3##S = *(const s16x8*)(c_ + OFF_W + (((16 * wq + li) * 256 + 3 * 64 + hi * 16) ^ SWZ(li))); \
      fB0##S = *(const s16x8*)(c_ + OFF_G + (((16 * wq + li) * 128 + 0 * 64 + hi * 16) ^ SWZ(li))); \
      fB1##S = *(const s16x8*)(c_ + OFF_G + (((16 * wq + li) * 128 + 1 * 64 + hi * 16) ^ SWZ(li))); \
      _Pragma("unroll") for (int r_ = 0; r_ < 4; ++r_)                        \
        u0##S[r_] = *(const float*)(c_ + OFF_U0 + s * 4096 +                  \
                                    ((16 * wq + hi * 4 + r_) * 16 + li) * 4); \
    } else {                                                                  \
      fA0##S = *(const s16x8*)(c_ + OFF_Q + (((16 * wq + li) * 256 + 0 * 64 + hi * 16) ^ SWZ(li))); \
      fA1##S = *(const s16x8*)(c_ + OFF_Q + (((16 * wq + li) * 256 + 1 * 64 + hi * 16) ^ SWZ(li))); \
      fA2##S = *(const s16x8*)(c_ + OFF_Q + (((16 * wq + li) * 256 + 2 * 64 + hi * 16) ^ SWZ(li))); \
      fA3##S = *(const s16x8*)(c_ + OFF_Q + (((16 * wq + li) * 256 + 3 * 64 + hi * 16) ^ SWZ(li))); \
      fB0##S = *(const s16x8*)(c_ + OFF_KD + ((((wq + 0) * 16 + li) * 128 + 0 * 64 + hi * 16) ^ SWZ(li))); \
      fB1##S = *(const s16x8*)(c_ + OFF_KD + ((((wq + 0) * 16 + li) * 128 + 1 * 64 + hi * 16) ^ SWZ(li))); \
      fC0##S = *(const s16x8*)(c_ + OFF_KD + ((((wq + 4) * 16 + li) * 128 + 0 * 64 + hi * 16) ^ SWZ(li))); \
      fC1##S = *(const s16x8*)(c_ + OFF_KD + ((((wq + 4) * 16 + li) * 128 + 1 * 64 + hi * 16) ^ SWZ(li))); \
      gr0##S = *(const float*)(c_ + OFF_GM + (16 * wq + hi * 4 + 0) * 4);     \
      gr1##S = *(const float*)(c_ + OFF_GM + (16 * wq + hi * 4 + 1) * 4);     \
      gr2##S = *(const float*)(c_ + OFF_GM + (16 * wq + hi * 4 + 2) * 4);     \
      gr3##S = *(const float*)(c_ + OFF_GM + (16 * wq + hi * 4 + 3) * 4);     \
      ge##S = *(const float*)(c_ + OFF_GM + 63 * 4);                          \
    }                                                                         \
  } while (0)

#define BODY(CUR, NXT, c)                                                     \
  do {                                                                        \
    if ((c) + 1 < NCH) LOADC(NXT, (c) + 1);                                   \
    s16x8 sfb0 = *(const s16x8*)(Stb + ((li * 256 + 0 * 64 + hi * 16) ^ SWZ(li))); \
    s16x8 sfb1 = *(const s16x8*)(Stb + ((li * 256 + 1 * 64 + hi * 16) ^ SWZ(li))); \
    s16x8 sfb2 = *(const s16x8*)(Stb + ((li * 256 + 2 * 64 + hi * 16) ^ SWZ(li))); \
    s16x8 sfb3 = *(const s16x8*)(Stb + ((li * 256 + 3 * 64 + hi * 16) ^ SWZ(li))); \
    if (grpA) {                                                               \
      f32x4 Y = u0##CUR;                                                      \
      Y = __builtin_amdgcn_mfma_f32_16x16x32_bf16(fA0##CUR, sfb0, Y, 0, 0, 0); \
      Y = __builtin_amdgcn_mfma_f32_16x16x32_bf16(fA1##CUR, sfb1, Y, 0, 0, 0); \
      Y = __builtin_amdgcn_mfma_f32_16x16x32_bf16(fA2##CUR, sfb2, Y, 0, 0, 0); \
      Y = __builtin_amdgcn_mfma_f32_16x16x32_bf16(fA3##CUR, sfb3, Y, 0, 0, 0); \
      _Pragma("unroll") for (int r_ = 0; r_ < 4; r_ += 2) {                   \
        int j_ = 16 * wq + hi * 4 + r_;                                       \
        unsigned pk_ = (unsigned)f2b(Y[r_]) | ((unsigned)f2b(Y[r_ + 1]) << 16); \
        *(unsigned*)(Ytb + ((li * 128 + j_ * 2) ^ SWZ(li))) = pk_;            \
      }                                                                       \
      LBAR();                                                                 \
      s16x8 yfb0 = *(const s16x8*)(Ytb + ((li * 128 + 0 * 64 + hi * 16) ^ SWZ(li))); \
      s16x8 yfb1 = *(const s16x8*)(Ytb + ((li * 128 + 1 * 64 + hi * 16) ^ SWZ(li))); \
      f32x4 O;                                                                \
      _Pragma("unroll") for (int r_ = 0; r_ < 4; ++r_)                        \
        O[r_] = Oa[(16 * wq + hi * 4 + r_) * 16 + li];                        \
      O = __builtin_amdgcn_mfma_f32_16x16x32_bf16(fB0##CUR, yfb0, O, 0, 0, 0); \
      O = __builtin_amdgcn_mfma_f32_16x16x32_bf16(fB1##CUR, yfb1, O, 0, 0, 0); \
      _Pragma("unroll") for (int r_ = 0; r_ < 4; ++r_) {                      \
        size_t oi_ = ((size_t)(b * T_LEN + (c) * 64 + 16 * wq + hi * 4 + r_) * H_N + h) * DV + s * 16 + li; \
        out[oi_] = O[r_];                                                     \
      }                                                                       \
    } else {                                                                  \
      f32x4 Oq = {0, 0, 0, 0};                                                \
      Oq = __builtin_amdgcn_mfma_f32_16x16x32_bf16(fA0##CUR, sfb0, Oq, 0, 0, 0); \
      Oq = __builtin_amdgcn_mfma_f32_16x16x32_bf16(fA1##CUR, sfb1, Oq, 0, 0, 0); \
      Oq = __builtin_amdgcn_mfma_f32_16x16x32_bf16(fA2##CUR, sfb2, Oq, 0, 0, 0); \
      Oq = __builtin_amdgcn_mfma_f32_16x16x32_bf16(fA3##CUR, sfb3, Oq, 0, 0, 0); \
      Oa[(16 * wq + hi * 4 + 0) * 16 + li] = gr0##CUR * Oq[0];                \
      Oa[(16 * wq + hi * 4 + 1) * 16 + li] = gr1##CUR * Oq[1];                \
      Oa[(16 * wq + hi * 4 + 2) * 16 + li] = gr2##CUR * Oq[2];                \
      Oa[(16 * wq + hi * 4 + 3) * 16 + li] = gr3##CUR * Oq[3];                \
      LBAR();                                                                 \
      s16x8 yfb0 = *(const s16x8*)(Ytb + ((li * 128 + 0 * 64 + hi * 16) ^ SWZ(li))); \
      s16x8 yfb1 = *(const s16x8*)(Ytb + ((li * 128 + 1 * 64 + hi * 16) ^ SWZ(li))); \
      {                                                                       \
        f32x4 acc;                                                            \
        _Pragma("unroll") for (int r_ = 0; r_ < 4; ++r_) acc[r_] = ge##CUR * S[0][r_]; \
        acc = __builtin_amdgcn_mfma_f32_16x16x32_bf16(fB0##CUR, yfb0, acc, 0, 0, 0); \
        acc = __builtin_amdgcn_mfma_f32_16x16x32_bf16(fB1##CUR, yfb1, acc, 0, 0, 0); \
        _Pragma("unroll") for (int r_ = 0; r_ < 4; ++r_) S[0][r_] = acc[r_];  \
      }                                                                       \
      {                                                                       \
        f32x4 acc;                                                            \
        _Pragma("unroll") for (int r_ = 0; r_ < 4; ++r_) acc[r_] = ge##CUR * S[1][r_]; \
        acc = __builtin_amdgcn_mfma_f32_16x16x32_bf16(fC0##CUR, yfb0, acc, 0, 0, 0); \
        acc = __builtin_amdgcn_mfma_f32_16x16x32_bf16(fC1##CUR, yfb1, acc, 0, 0, 0); \
        _Pragma("unroll") for (int r_ = 0; r_ < 4; ++r_) S[1][r_] = acc[r_];  \
      }                                                                       \
      WRITE_ST();                                                             \
    }                                                                         \
    LBAR();                                                                   \
  } while (0)

extern "C" __global__ void __launch_bounds__(512, 1) gdn_p2(
    const float* __restrict__ S0, float* __restrict__ out,
    const char* __restrict__ ws) {
  __shared__ unsigned char Stb[4096];   // S^T bf16 [16 col][128 d], swz
  __shared__ unsigned char Ytb[2048];   // Y^T bf16 [16 col][64 j], swz
  __shared__ float Oa[1024];            // 64 rows x 16 cols f32

  const int bid = blockIdx.x;
  const int bh = bid & 31, s = bid >> 5;   // siblings share (bid mod 8) -> XCD
  const int b = bh >> 4, h = bh & 15;
  const int tid = threadIdx.x;
  const int w = tid >> 6;                   // 0..7
  const int lane = tid & 63, li = lane & 15, hi = lane >> 4;
  const int wq = w & 3;
  const bool grpA = (w < 4);
  const char* wsbase = ws + (size_t)bh * 64 * CH_B;

  float S[2][4];
  if (!grpA) {
#pragma unroll
    for (int t = 0; t < 2; ++t)
#pragma unroll
      for (int r = 0; r < 4; ++r) {
        int d = (wq + 4 * t) * 16 + hi * 4 + r;
        S[t][r] = S0[((size_t)bh * 128 + d) * 128 + s * 16 + li];
      }
  }
#define WRITE_ST()                                                            \
  do {                                                                        \
    _Pragma("unroll") for (int t = 0; t < 2; ++t)                             \
        _Pragma("unroll") for (int r = 0; r < 4; r += 2) {                    \
      int d = (wq + 4 * t) * 16 + hi * 4 + r;                                 \
      unsigned pk = (unsigned)f2b(S[t][r]) | ((unsigned)f2b(S[t][r + 1]) << 16); \
      *(unsigned*)(Stb + ((li * 256 + d * 2) ^ SWZ(li))) = pk;                \
    }                                                                         \
  } while (0)

  if (!grpA) WRITE_ST();
  DECLBUF(A_)
  DECLBUF(B_)
  LOADC(A_, 0);
  LBAR();  // Stb visible

#pragma unroll 1
  for (int cc = 0; cc < NCH; cc += 2) {
    BODY(A_, B_, cc);
    BODY(B_, A_, cc + 1);
  }

  if (!grpA) {
#pragma unroll
    for (int t = 0; t < 2; ++t)
#pragma unroll
      for (int r = 0; r < 4; ++r) {
        int d = (wq + 4 * t) * 16 + hi * 4 + r;
        out[(size_t)(2 * T_LEN * H_N * DV) + ((size_t)bh * 128 + d) * 128 + s * 16 + li] = S[t][r];
      }
  }
}

// ---------------- Fallback (round-5 kernel, used only if ws too small) ----
#define COLS 16
#define CHUNK 16
#define STEP_B 8192u
#define AB_B 64u
#define OSTRIDE (H_N * DV)
template <int CTRL>
__device__ __forceinline__ float dpp_add(float x) {
  int y = __builtin_amdgcn_update_dpp(0, __float_as_int(x), CTRL, 0xF, 0xF, true);
  return x + __int_as_float(y);
}
__device__ __forceinline__ float red16(float x) {
  x = dpp_add<0xB1>(x); x = dpp_add<0x4E>(x);
  x = dpp_add<0x124>(x); x = dpp_add<0x128>(x);
  return x;
}
extern "C" __global__ void __launch_bounds__(256, 1) gdn_fallback(
    const float* __restrict__ q, const float* __restrict__ k,
    const float* __restrict__ v, const float* __restrict__ al,
    const float* __restrict__ be, const float* __restrict__ S0,
    float* __restrict__ out) {
  __shared__ float kb[2][CHUNK * DK];
  __shared__ float qb[2][CHUNK * DK];
  __shared__ float vb[2][CHUNK * COLS];
  __shared__ float abuf[2][64];
  __shared__ float bbuf[2][64];
  const int bid = blockIdx.x;
  const int bh = bid & 31, g = bid >> 5;
  const int b = bh >> 4, h = bh & 15;
  const int tid = threadIdx.x;
  const int cl = tid >> 4, li = tid & 15, lane = tid & 63, wid = tid >> 6;
  const int col = g * COLS + cl, d0 = li * 8;
  const size_t bh_qk = ((size_t)b * T_LEN * H_N + h) * DK;
  const size_t bh_v = ((size_t)b * T_LEN * H_N + h) * DV;
  const size_t bh_ab = (size_t)b * T_LEN * H_N + h;
  const int fo0 = wid * 2048 + lane * 16, fo1 = fo0 + 1024;
  const char* kg0 = (const char*)(k + bh_qk) + (size_t)(fo0 >> 9) * STEP_B + (fo0 & 511);
  const char* kg1 = (const char*)(k + bh_qk) + (size_t)(fo1 >> 9) * STEP_B + (fo1 & 511);
  const char* qg0 = (const char*)(q + bh_qk) + (size_t)(fo0 >> 9) * STEP_B + (fo0 & 511);
  const char* qg1 = (const char*)(q + bh_qk) + (size_t)(fo1 >> 9) * STEP_B + (fo1 & 511);
  const int fv = lane * 16;
  const char* vg = (const char*)(v + bh_v + g * COLS) + (size_t)(fv >> 6) * STEP_B + (fv & 63);
  const int lcl = lane < 16 ? lane : 15;
  const char* ag = (const char*)(al + bh_ab) + (size_t)lcl * AB_B;
  const char* bg = (const char*)(be + bh_ab) + (size_t)lcl * AB_B;
#define STAGEF(CI, P) do { \
    const size_t off = (size_t)(CI) * (CHUNK * STEP_B); \
    const size_t offab = (size_t)(CI) * (CHUNK * AB_B); \
    GLDS16(kg0 + off, &kb[P][wid * 512]); GLDS16(kg1 + off, &kb[P][wid * 512 + 256]); \
    GLDS16(qg0 + off, &qb[P][wid * 512]); GLDS16(qg1 + off, &qb[P][wid * 512 + 256]); \
    if (wid == 0) GLDS16(vg + off, &vb[P][0]); \
    else if (wid == 1) GLDS4(ag + offab, &abuf[P][0]); \
    else if (wid == 2) GLDS4(bg + offab, &bbuf[P][0]); \
  } while (0)
  float sv[8];
  const float* s0p = S0 + ((size_t)(b * H_N + h) * DK + d0) * DV + col;
#pragma unroll
  for (int j = 0; j < 8; ++j) sv[j] = s0p[(size_t)j * DV];
  STAGEF(0, 0);
  __syncthreads();
  float* op = out + bh_v + col;
  for (int ci = 0; ci < T_LEN / CHUNK; ++ci) {
    const int p = ci & 1;
    if (ci + 1 < T_LEN / CHUNK) STAGEF(ci + 1, p ^ 1);
    const float* kc = kb[p]; const float* qc = qb[p]; const float* vc = vb[p];
    const float* ac = abuf[p]; const float* bc = bbuf[p];
#pragma unroll
    for (int j = 0; j < CHUNK; ++j) {
      f32x4 kA = *(const f32x4*)(kc + j * DK + d0);
      f32x4 kB = *(const f32x4*)(kc + j * DK + d0 + 4);
      f32x4 qA = *(const f32x4*)(qc + j * DK + d0);
      f32x4 qB = *(const f32x4*)(qc + j * DK + d0 + 4);
      float vv = vc[j * COLS + cl], aa = ac[j], bv = bc[j];
      float kk[8] = {kA[0], kA[1], kA[2], kA[3], kB[0], kB[1], kB[2], kB[3]};
      float qq[8] = {qA[0], qA[1], qA[2], qA[3], qB[0], qB[1], qB[2], qB[3]};
      float pk0 = kk[0] * sv[0], pk1 = kk[1] * sv[1];
      float pu0 = qq[0] * sv[0], pu1 = qq[1] * sv[1];
      float pg0 = kk[0] * qq[0], pg1 = kk[1] * qq[1];
#pragma unroll
      for (int m = 2; m < 8; m += 2) {
        pk0 = fmaf(kk[m], sv[m], pk0); pk1 = fmaf(kk[m + 1], sv[m + 1], pk1);
        pu0 = fmaf(qq[m], sv[m], pu0); pu1 = fmaf(qq[m + 1], sv[m + 1], pu1);
        pg0 = fmaf(kk[m], qq[m], pg0); pg1 = fmaf(kk[m + 1], qq[m + 1], pg1);
      }
      float pk = red16(pk0 + pk1), pu = red16(pu0 + pu1), pg = red16(pg0 + pg1);
      float tmp = fmaf(-(bv * aa), pk, bv * vv);
#pragma unroll
      for (int m = 0; m < 8; ++m) sv[m] = fmaf(aa, sv[m], kk[m] * tmp);
      if (li == 0) op[(size_t)(ci * CHUNK + j) * OSTRIDE] = fmaf(pg, tmp, aa * pu);
    }
    __syncthreads();
  }
  float* sf = out + (size_t)2 * T_LEN * H_N * DV + ((size_t)(b * H_N + h) * DK + d0) * DV + col;
#pragma unroll
  for (int j = 0; j < 8; ++j) sf[(size_t)j * DV] = sv[j];
}

extern "C" void kernel_launch(void* const* d_in, const int* in_sizes, int n_in,
                              void* d_out, int out_size, void* d_ws,
                              size_t ws_size, hipStream_t stream) {
  const float* q = (const float*)d_in[0];
  const float* k = (const float*)d_in[1];
  const float* v = (const float*)d_in[2];
  const float* al = (const float*)d_in[3];
  const float* be = (const float*)d_in[4];
  const float* S0 = (const float*)d_in[5];
  float* out = (float*)d_out;

  if (ws_size >= WS_NEED) {
    gdn_p1<<<dim3(2048), dim3(256), 0, stream>>>(q, k, v, al, be, (char*)d_ws);
    gdn_p2<<<dim3(256), dim3(512), 0, stream>>>(S0, out, (const char*)d_ws);
  } else {
    gdn_fallback<<<dim3(256), dim3(256), 0, stream>>>(q, k, v, al, be, S0, out);
  }
}

// Round 16
// 239.254 us; speedup vs baseline: 3.4235x; 1.0718x over previous
//
#include <hip/hip_runtime.h>

// Problem dims: B=2, T=4096, H=16, Dk=Dv=128. Chunked delta rule, L=64.
#define T_LEN 4096
#define H_N   16
#define DK    128
#define DV    128
#define LCH   64
#define NCH   64

typedef float f32x4 __attribute__((ext_vector_type(4)));
typedef short s16x8 __attribute__((ext_vector_type(8)));

// workspace layout per (head,chunk), bytes
#define OFF_U0 0        // [8 slices][64 rows][16 cols] bf16 (round-16: was f32)
#define OFF_W  32768    // 64x128 bf16, XOR-swizzled rows (negated W)
#define OFF_Q  49152    // 64x128 bf16, XOR-swizzled rows (gamma-less Q)
#define OFF_KD 65536    // 128x64 bf16, XOR-swizzled rows ([d][j] = rr_j k[j][d])
#define OFF_G  81920    // 64x64 bf16, XOR-swizzled rows
#define OFF_GM 90112    // 64 f32 (gamma_i = exp(cumsum ln a))
#define CH_B   90368ull
#define WS_NEED (2048ull * CH_B)

#define SWZ(row) (((row)&7) << 4)

// LDS strides (padded; round-12)
#define AST 68
#define RST 132

__device__ __forceinline__ unsigned short f2b(float x) {
  unsigned u = __float_as_uint(x);
  return (unsigned short)((u + 0x7FFF + ((u >> 16) & 1)) >> 16);
}

// Async global->LDS (p1 + fallback only)
#define GLDS16(gp, lp)                                                        \
  __builtin_amdgcn_global_load_lds(                                           \
      (const __attribute__((address_space(1))) void*)(gp),                    \
      (__attribute__((address_space(3))) void*)(lp), 16, 0, 0)
#define GLDS4(gp, lp)                                                         \
  __builtin_amdgcn_global_load_lds(                                           \
      (const __attribute__((address_space(1))) void*)(gp),                    \
      (__attribute__((address_space(3))) void*)(lp), 4, 0, 0)

// LDS-only barrier: orders ds ops across waves WITHOUT touching vmcnt.
#define LBAR()                                                                \
  do {                                                                        \
    asm volatile("s_waitcnt lgkmcnt(0)" ::: "memory");                        \
    __builtin_amdgcn_s_barrier();                                             \
    __builtin_amdgcn_sched_barrier(0);                                        \
  } while (0)

// ---------------- Phase 1: per-(head,chunk) UT transform ----------------
// Off-diag: 128 threads x (4 rows x 4 cols) -> Y[j] slice read once per 4
// dst rows (round-15).
__device__ void solve64(float* RHS, const float* A, int tid) {
#pragma unroll 1
  for (int I = 0; I < 4; ++I) {
    if (I > 0) {
      if (tid < 128) {
        const int rg = tid >> 5;          // 0..3 -> 4 dst rows each
        const int r0 = 16 * I + rg * 4;
        const int cs = (tid & 31) * 4;    // 4-col slice
        f32x4 acc0 = *(const f32x4*)(RHS + (r0 + 0) * RST + cs);
        f32x4 acc1 = *(const f32x4*)(RHS + (r0 + 1) * RST + cs);
        f32x4 acc2 = *(const f32x4*)(RHS + (r0 + 2) * RST + cs);
        f32x4 acc3 = *(const f32x4*)(RHS + (r0 + 3) * RST + cs);
        for (int j = 0; j < 16 * I; ++j) {
          f32x4 yv = *(const f32x4*)(RHS + j * RST + cs);
          float a0 = A[(r0 + 0) * AST + j];   // banks differ by 4/row: free
          float a1 = A[(r0 + 1) * AST + j];
          float a2 = A[(r0 + 2) * AST + j];
          float a3 = A[(r0 + 3) * AST + j];
#pragma unroll
          for (int e = 0; e < 4; ++e) {
            acc0[e] = fmaf(-a0, yv[e], acc0[e]);
            acc1[e] = fmaf(-a1, yv[e], acc1[e]);
            acc2[e] = fmaf(-a2, yv[e], acc2[e]);
            acc3[e] = fmaf(-a3, yv[e], acc3[e]);
          }
        }
        *(f32x4*)(RHS + (r0 + 0) * RST + cs) = acc0;
        *(f32x4*)(RHS + (r0 + 1) * RST + cs) = acc1;
        *(f32x4*)(RHS + (r0 + 2) * RST + cs) = acc2;
        *(f32x4*)(RHS + (r0 + 3) * RST + cs) = acc3;
      }
      __syncthreads();
    }
    // diagonal 16x16 block, serial rows, 128 threads (1 col each)
    if (tid < 128) {
      const int col = tid;
      float y[16];
#pragma unroll
      for (int r = 0; r < 16; ++r) y[r] = RHS[(16 * I + r) * RST + col];
#pragma unroll
      for (int r = 1; r < 16; ++r) {
        float t0 = 0.f, t1 = 0.f;
#pragma unroll
        for (int j = 0; j < 15; ++j)
          if (j < r) {
            float av = A[(16 * I + r) * AST + 16 * I + j];
            if (j & 1) t1 = fmaf(av, y[j], t1);
            else       t0 = fmaf(av, y[j], t0);
          }
        y[r] -= t0 + t1;
      }
#pragma unroll
      for (int r = 0; r < 16; ++r) RHS[(16 * I + r) * RST + col] = y[r];
    }
    __syncthreads();
  }
}

extern "C" __global__ void __launch_bounds__(256) gdn_p1(
    const float* __restrict__ q, const float* __restrict__ k,
    const float* __restrict__ v, const float* __restrict__ al,
    const float* __restrict__ be, char* __restrict__ ws) {
  __shared__ __align__(16) unsigned char big[34048];
  __shared__ __align__(16) float A_s[64 * AST];
  __shared__ float g_s[64], bb_s[64], sc_s[64];
  unsigned char* Kb = big;
  unsigned char* Qb = big + 16384;
  float* RHS = (float*)big;

  const int bid = blockIdx.x;
  const int bh = bid & 31, c = bid >> 5;
  const int b = bh >> 4, h = bh & 15;
  const int tid = threadIdx.x;
  const int t0 = c * LCH;
  char* wsc = ws + (size_t)(bh * 64 + c) * CH_B;

  if (tid < 64) {
    size_t gi = (size_t)(b * T_LEN + t0 + tid) * H_N + h;
    float x = __logf(al[gi]);
    bb_s[tid] = be[gi];
#pragma unroll
    for (int d = 1; d < 64; d <<= 1) {
      float yv = __shfl_up(x, d, 64);
      if (tid >= d) x += yv;
    }
    float gam = __expf(x);
    g_s[tid] = x;
    sc_s[tid] = gam;
    *(float*)(wsc + OFF_GM + tid * 4) = gam;
  }

  for (int idx = tid; idx < 1024; idx += 256) {
    int row = idx >> 4, grp = idx & 15;
    size_t go = ((size_t)(b * T_LEN + t0 + row) * H_N + h) * DK + grp * 8;
    float4 ka = *(const float4*)(k + go);
    float4 kb2 = *(const float4*)(k + go + 4);
    float4 qa = *(const float4*)(q + go);
    float4 qb2 = *(const float4*)(q + go + 4);
    union { unsigned short u[8]; uint4 v4; } tk, tq;
    tk.u[0] = f2b(ka.x); tk.u[1] = f2b(ka.y); tk.u[2] = f2b(ka.z); tk.u[3] = f2b(ka.w);
    tk.u[4] = f2b(kb2.x); tk.u[5] = f2b(kb2.y); tk.u[6] = f2b(kb2.z); tk.u[7] = f2b(kb2.w);
    tq.u[0] = f2b(qa.x); tq.u[1] = f2b(qa.y); tq.u[2] = f2b(qa.z); tq.u[3] = f2b(qa.w);
    tq.u[4] = f2b(qb2.x); tq.u[5] = f2b(qb2.y); tq.u[6] = f2b(qb2.z); tq.u[7] = f2b(qb2.w);
    int la = (row * 256 + grp * 16) ^ SWZ(row);
    *(uint4*)(Kb + la) = tk.v4;
    *(uint4*)(Qb + la) = tq.v4;
    *(uint4*)(wsc + OFF_Q + la) = tq.v4;
  }
  __syncthreads();

  const int w = tid >> 6, l = tid & 63, li = l & 15, hi = l >> 4;
  f32x4 aK[4], aQ[4];
#pragma unroll
  for (int jt = 0; jt < 4; ++jt) { aK[jt] = (f32x4){0, 0, 0, 0}; aQ[jt] = (f32x4){0, 0, 0, 0}; }
#pragma unroll
  for (int ks = 0; ks < 4; ++ks) {
    int rowA = 16 * w + li;
    int oa = (rowA * 256 + ks * 64 + hi * 16) ^ SWZ(rowA);
    s16x8 fa = *(const s16x8*)(Kb + oa);
    s16x8 fq = *(const s16x8*)(Qb + oa);
#pragma unroll
    for (int jt = 0; jt < 4; ++jt) {
      int rowB = 16 * jt + li;
      s16x8 fb = *(const s16x8*)(Kb + ((rowB * 256 + ks * 64 + hi * 16) ^ SWZ(rowB)));
      aK[jt] = __builtin_amdgcn_mfma_f32_16x16x32_bf16(fa, fb, aK[jt], 0, 0, 0);
      aQ[jt] = __builtin_amdgcn_mfma_f32_16x16x32_bf16(fq, fb, aQ[jt], 0, 0, 0);
    }
  }
#pragma unroll
  for (int jt = 0; jt < 4; ++jt)
#pragma unroll
    for (int r = 0; r < 4; ++r) {
      int i = 16 * w + hi * 4 + r, j = 16 * jt + li;   // C layout (m89)
      float e = __expf(g_s[i] - g_s[j]);
      A_s[i * AST + j] = (j < i) ? bb_s[i] * e * aK[jt][r] : 0.f;
      *(unsigned short*)(wsc + OFF_G + ((i * 128 + j * 2) ^ SWZ(i))) =
          f2b((j <= i) ? e * aQ[jt][r] : 0.f);
    }
  __syncthreads();

  for (int idx = tid; idx < 2048; idx += 256) {
    int row = idx >> 5, c4 = idx & 31;
    float4 vv = *(const float4*)(v + ((size_t)(b * T_LEN + t0 + row) * H_N + h) * DV + c4 * 4);
    float s = bb_s[row];
    float4 o = {s * vv.x, s * vv.y, s * vv.z, s * vv.w};
    *(float4*)(RHS + row * RST + c4 * 4) = o;
  }
  __syncthreads();
  solve64(RHS, A_s, tid);
  // U0 store as bf16 (round-16): [slice 8][row 64][16 cols] bf16; one
  // uint4 (8 bf16 = 8 cols) per iter.
  for (int idx = tid; idx < 1024; idx += 256) {
    int row = idx >> 4, cg = idx & 15;  // cg: 8-col group
    const float* p = RHS + row * RST + cg * 8;
    union { unsigned u2[4]; uint4 v4; } t;
#pragma unroll
    for (int e = 0; e < 4; ++e)
      t.u2[e] = (unsigned)f2b(p[2 * e]) | ((unsigned)f2b(p[2 * e + 1]) << 16);
    *(uint4*)(wsc + OFF_U0 + (cg >> 1) * 2048 + row * 32 + (cg & 1) * 16) = t.v4;
  }
  __syncthreads();

  for (int idx = tid; idx < 2048; idx += 256) {
    int row = idx >> 5, c4 = idx & 31;
    float4 kv = *(const float4*)(k + ((size_t)(b * T_LEN + t0 + row) * H_N + h) * DK + c4 * 4);
    float s = bb_s[row] * sc_s[row];
    float4 o = {s * kv.x, s * kv.y, s * kv.z, s * kv.w};
    *(float4*)(RHS + row * RST + c4 * 4) = o;
  }
  __syncthreads();
  solve64(RHS, A_s, tid);
  for (int idx = tid; idx < 1024; idx += 256) {
    int row = idx >> 4, g8 = idx & 15;
    const float* p = RHS + row * RST + g8 * 8;
    union { unsigned short u[8]; uint4 v4; } t;
#pragma unroll
    for (int e = 0; e < 8; ++e) t.u[e] = f2b(-p[e]);
    *(uint4*)(wsc + OFF_W + ((row * 256 + g8 * 16) ^ SWZ(row))) = t.v4;
  }
  __syncthreads();

  if (tid < 64) sc_s[tid] = __expf(g_s[63] - g_s[tid]);  // rr_j
  __syncthreads();
  float* Kf = (float*)big;  // 32 x 132 f32
#pragma unroll 1
  for (int p = 0; p < 2; ++p) {
    for (int idx = tid; idx < 1024; idx += 256) {
      int r = idx >> 5, c4 = idx & 31;
      float4 kv = *(const float4*)(k + ((size_t)(b * T_LEN + t0 + 32 * p + r) * H_N + h) * DK + c4 * 4);
      *(float4*)(Kf + r * 132 + c4 * 4) = kv;
    }
    __syncthreads();
    // Kdt paired u32 stores (round-16): 8 iters of 2 packed j's (was 16
    // scalar u16 stores) -> half the sub-word store instructions.
#pragma unroll
    for (int m = 0; m < 8; ++m) {
      int flat = m * 256 + tid;            // 128 d x 16 j-pairs
      int jp = flat & 15, d = flat >> 4;
      int j0 = 2 * jp, j1 = 2 * jp + 1;
      float v0 = sc_s[32 * p + j0] * Kf[j0 * 132 + d];
      float v1 = sc_s[32 * p + j1] * Kf[j1 * 132 + d];
      unsigned pk = (unsigned)f2b(v0) | ((unsigned)f2b(v1) << 16);
      *(unsigned*)(wsc + OFF_KD + ((d * 128 + (32 * p + j0) * 2) ^ SWZ(d))) = pk;
    }
    __syncthreads();
  }
}

// ---------------- Phase 2: role-split + 2-deep chunk pipeline ------------
#define DECLBUF(S)                                                            \
  s16x8 fA0##S, fA1##S, fA2##S, fA3##S, fB0##S, fB1##S, fC0##S, fC1##S;       \
  f32x4 u0##S;                                                                \
  float gr0##S, gr1##S, gr2##S, gr3##S, ge##S;

#define LOADC(S, CI)                                                          \
  do {                                                                        \
    const char* c_ = wsbase + (size_t)(CI) * CH_B;                            \
    if (grpA) {                                                               \
      fA0##S = *(const s16x8*)(c_ + OFF_W + (((16 * wq + li) * 256 + 0 * 64 + hi * 16) ^ SWZ(li))); \
      fA1##S = *(const s16x8*)(c_ + OFF_W + (((16 * wq + li) * 256 + 1 * 64 + hi * 16) ^ SWZ(li))); \
      fA2##S = *(const s16x8*)(c_ + OFF_W + (((16 * wq + li) * 256 + 2 * 64 + hi * 16) ^ SWZ(li))); \
      fA3##S = *(const s16x8*)(c_ + OFF_W + (((16 * wq + li) * 256 + 3 * 64 + hi * 16) ^ SWZ(li))); \
      fB0##S = *(const s16x8*)(c_ + OFF_G + (((16 * wq + li) * 128 + 0 * 64 + hi * 16) ^ SWZ(li))); \
      fB1##S = *(const s16x8*)(c_ + OFF_G + (((16 * wq + li) * 128 + 1 * 64 + hi * 16) ^ SWZ(li))); \
      _Pragma("unroll") for (int r_ = 0; r_ < 4; ++r_) {                      \
        unsigned short us_ = *(const unsigned short*)(c_ + OFF_U0 + s * 2048 + \
                                 (16 * wq + hi * 4 + r_) * 32 + li * 2);      \
        u0##S[r_] = __uint_as_float((unsigned)us_ << 16);                     \
      }                                                                       \
    } else {                                                                  \
      fA0##S = *(const s16x8*)(c_ + OFF_Q + (((16 * wq + li) * 256 + 0 * 64 + hi * 16) ^ SWZ(li))); \
      fA1##S = *(const s16x8*)(c_ + OFF_Q + (((16 * wq + li) * 256 + 1 * 64 + hi * 16) ^ SWZ(li))); \
      fA2##S = *(const s16x8*)(c_ + OFF_Q + (((16 * wq + li) * 256 + 2 * 64 + hi * 16) ^ SWZ(li))); \
      fA3##S = *(const s16x8*)(c_ + OFF_Q + (((16 * wq + li) * 256 + 3 * 64 + hi * 16) ^ SWZ(li))); \
      fB0##S = *(const s16x8*)(c_ + OFF_KD + ((((wq + 0) * 16 + li) * 128 + 0 * 64 + hi * 16) ^ SWZ(li))); \
      fB1##S = *(const s16x8*)(c_ + OFF_KD + ((((wq + 0) * 16 + li) * 128 + 1 * 64 + hi * 16) ^ SWZ(li))); \
      fC0##S = *(const s16x8*)(c_ + OFF_KD + ((((wq + 4) * 16 + li) * 128 + 0 * 64 + hi * 16) ^ SWZ(li))); \
      fC1##S = *(const s16x8*)(c_ + OFF_KD + ((((wq + 4) * 16 + li) * 128 + 1 * 64 + hi * 16) ^ SWZ(li))); \
      gr0##S = *(const float*)(c_ + OFF_GM + (16 * wq + hi * 4 + 0) * 4);     \
      gr1##S = *(const float*)(c_ + OFF_GM + (16 * wq + hi * 4 + 1) * 4);     \
      gr2##S = *(const float*)(c_ + OFF_GM + (16 * wq + hi * 4 + 2) * 4);     \
      gr3##S = *(const float*)(c_ + OFF_GM + (16 * wq + hi * 4 + 3) * 4);     \
      ge##S = *(const float*)(c_ + OFF_GM + 63 * 4);                          \
    }                                                                         \
  } while (0)

#define BODY(CUR, NXT, c)                                                     \
  do {                                                                        \
    if ((c) + 1 < NCH) LOADC(NXT, (c) + 1);                                   \
    s16x8 sfb0 = *(const s16x8*)(Stb + ((li * 256 + 0 * 64 + hi * 16) ^ SWZ(li))); \
    s16x8 sfb1 = *(const s16x8*)(Stb + ((li * 256 + 1 * 64 + hi * 16) ^ SWZ(li))); \
    s16x8 sfb2 = *(const s16x8*)(Stb + ((li * 256 + 2 * 64 + hi * 16) ^ SWZ(li))); \
    s16x8 sfb3 = *(const s16x8*)(Stb + ((li * 256 + 3 * 64 + hi * 16) ^ SWZ(li))); \
    if (grpA) {                                                               \
      f32x4 Y = u0##CUR;                                                      \
      Y = __builtin_amdgcn_mfma_f32_16x16x32_bf16(fA0##CUR, sfb0, Y, 0, 0, 0); \
      Y = __builtin_amdgcn_mfma_f32_16x16x32_bf16(fA1##CUR, sfb1, Y, 0, 0, 0); \
      Y = __builtin_amdgcn_mfma_f32_16x16x32_bf16(fA2##CUR, sfb2, Y, 0, 0, 0); \
      Y = __builtin_amdgcn_mfma_f32_16x16x32_bf16(fA3##CUR, sfb3, Y, 0, 0, 0); \
      _Pragma("unroll") for (int r_ = 0; r_ < 4; r_ += 2) {                   \
        int j_ = 16 * wq + hi * 4 + r_;                                       \
        unsigned pk_ = (unsigned)f2b(Y[r_]) | ((unsigned)f2b(Y[r_ + 1]) << 16); \
        *(unsigned*)(Ytb + ((li * 128 + j_ * 2) ^ SWZ(li))) = pk_;            \
      }                                                                       \
      LBAR();                                                                 \
      s16x8 yfb0 = *(const s16x8*)(Ytb + ((li * 128 + 0 * 64 + hi * 16) ^ SWZ(li))); \
      s16x8 yfb1 = *(const s16x8*)(Ytb + ((li * 128 + 1 * 64 + hi * 16) ^ SWZ(li))); \
      f32x4 O;                                                                \
      _Pragma("unroll") for (int r_ = 0; r_ < 4; ++r_)                        \
        O[r_] = Oa[(16 * wq + hi * 4 + r_) * 16 + li];                        \
      O = __builtin_amdgcn_mfma_f32_16x16x32_bf16(fB0##CUR, yfb0, O, 0, 0, 0); \
      O = __builtin_amdgcn_mfma_f32_16x16x32_bf16(fB1##CUR, yfb1, O, 0, 0, 0); \
      _Pragma("unroll") for (int r_ = 0; r_ < 4; ++r_) {                      \
        size_t oi_ = ((size_t)(b * T_LEN + (c) * 64 + 16 * wq + hi * 4 + r_) * H_N + h) * DV + s * 16 + li; \
        out[oi_] = O[r_];                                                     \
      }                                                                       \
    } else {                                                                  \
      f32x4 Oq = {0, 0, 0, 0};                                                \
      Oq = __builtin_amdgcn_mfma_f32_16x16x32_bf16(fA0##CUR, sfb0, Oq, 0, 0, 0); \
      Oq = __builtin_amdgcn_mfma_f32_16x16x32_bf16(fA1##CUR, sfb1, Oq, 0, 0, 0); \
      Oq = __builtin_amdgcn_mfma_f32_16x16x32_bf16(fA2##CUR, sfb2, Oq, 0, 0, 0); \
      Oq = __builtin_amdgcn_mfma_f32_16x16x32_bf16(fA3##CUR, sfb3, Oq, 0, 0, 0); \
      Oa[(16 * wq + hi * 4 + 0) * 16 + li] = gr0##CUR * Oq[0];                \
      Oa[(16 * wq + hi * 4 + 1) * 16 + li] = gr1##CUR * Oq[1];                \
      Oa[(16 * wq + hi * 4 + 2) * 16 + li] = gr2##CUR * Oq[2];                \
      Oa[(16 * wq + hi * 4 + 3) * 16 + li] = gr3##CUR * Oq[3];                \
      LBAR();                                                                 \
      s16x8 yfb0 = *(const s16x8*)(Ytb + ((li * 128 + 0 * 64 + hi * 16) ^ SWZ(li))); \
      s16x8 yfb1 = *(const s16x8*)(Ytb + ((li * 128 + 1 * 64 + hi * 16) ^ SWZ(li))); \
      {                                                                       \
        f32x4 acc;                                                            \
        _Pragma("unroll") for (int r_ = 0; r_ < 4; ++r_) acc[r_] = ge##CUR * S[0][r_]; \
        acc = __builtin_amdgcn_mfma_f32_16x16x32_bf16(fB0##CUR, yfb0, acc, 0, 0, 0); \
        acc = __builtin_amdgcn_mfma_f32_16x16x32_bf16(fB1##CUR, yfb1, acc, 0, 0, 0); \
        _Pragma("unroll") for (int r_ = 0; r_ < 4; ++r_) S[0][r_] = acc[r_];  \
      }                                                                       \
      {                                                                       \
        f32x4 acc;                                                            \
        _Pragma("unroll") for (int r_ = 0; r_ < 4; ++r_) acc[r_] = ge##CUR * S[1][r_]; \
        acc = __builtin_amdgcn_mfma_f32_16x16x32_bf16(fC0##CUR, yfb0, acc, 0, 0, 0); \
        acc = __builtin_amdgcn_mfma_f32_16x16x32_bf16(fC1##CUR, yfb1, acc, 0, 0, 0); \
        _Pragma("unroll") for (int r_ = 0; r_ < 4; ++r_) S[1][r_] = acc[r_];  \
      }                                                                       \
      WRITE_ST();                                                             \
    }                                                                         \
    LBAR();                                                                   \
  } while (0)

extern "C" __global__ void __launch_bounds__(512, 1) gdn_p2(
    const float* __restrict__ S0, float* __restrict__ out,
    const char* __restrict__ ws) {
  __shared__ unsigned char Stb[4096];   // S^T bf16 [16 col][128 d], swz
  __shared__ unsigned char Ytb[2048];   // Y^T bf16 [16 col][64 j], swz
  __shared__ float Oa[1024];            // 64 rows x 16 cols f32

  const int bid = blockIdx.x;
  const int bh = bid & 31, s = bid >> 5;   // siblings share (bid mod 8) -> XCD
  const int b = bh >> 4, h = bh & 15;
  const int tid = threadIdx.x;
  const int w = tid >> 6;                   // 0..7
  const int lane = tid & 63, li = lane & 15, hi = lane >> 4;
  const int wq = w & 3;
  const bool grpA = (w < 4);
  const char* wsbase = ws + (size_t)bh * 64 * CH_B;

  float S[2][4];
  if (!grpA) {
#pragma unroll
    for (int t = 0; t < 2; ++t)
#pragma unroll
      for (int r = 0; r < 4; ++r) {
        int d = (wq + 4 * t) * 16 + hi * 4 + r;
        S[t][r] = S0[((size_t)bh * 128 + d) * 128 + s * 16 + li];
      }
  }
#define WRITE_ST()                                                            \
  do {                                                                        \
    _Pragma("unroll") for (int t = 0; t < 2; ++t)                             \
        _Pragma("unroll") for (int r = 0; r < 4; r += 2) {                    \
      int d = (wq + 4 * t) * 16 + hi * 4 + r;                                 \
      unsigned pk = (unsigned)f2b(S[t][r]) | ((unsigned)f2b(S[t][r + 1]) << 16); \
      *(unsigned*)(Stb + ((li * 256 + d * 2) ^ SWZ(li))) = pk;                \
    }                                                                         \
  } while (0)

  if (!grpA) WRITE_ST();
  DECLBUF(A_)
  DECLBUF(B_)
  LOADC(A_, 0);
  LBAR();  // Stb visible

#pragma unroll 1
  for (int cc = 0; cc < NCH; cc += 2) {
    BODY(A_, B_, cc);
    BODY(B_, A_, cc + 1);
  }

  if (!grpA) {
#pragma unroll
    for (int t = 0; t < 2; ++t)
#pragma unroll
      for (int r = 0; r < 4; ++r) {
        int d = (wq + 4 * t) * 16 + hi * 4 + r;
        out[(size_t)(2 * T_LEN * H_N * DV) + ((size_t)bh * 128 + d) * 128 + s * 16 + li] = S[t][r];
      }
  }
}

// ---------------- Fallback (round-5 kernel, used only if ws too small) ----
#define COLS 16
#define CHUNK 16
#define STEP_B 8192u
#define AB_B 64u
#define OSTRIDE (H_N * DV)
template <int CTRL>
__device__ __forceinline__ float dpp_add(float x) {
  int y = __builtin_amdgcn_update_dpp(0, __float_as_int(x), CTRL, 0xF, 0xF, true);
  return x + __int_as_float(y);
}
__device__ __forceinline__ float red16(float x) {
  x = dpp_add<0xB1>(x); x = dpp_add<0x4E>(x);
  x = dpp_add<0x124>(x); x = dpp_add<0x128>(x);
  return x;
}
extern "C" __global__ void __launch_bounds__(256, 1) gdn_fallback(
    const float* __restrict__ q, const float* __restrict__ k,
    const float* __restrict__ v, const float* __restrict__ al,
    const float* __restrict__ be, const float* __restrict__ S0,
    float* __restrict__ out) {
  __shared__ float kb[2][CHUNK * DK];
  __shared__ float qb[2][CHUNK * DK];
  __shared__ float vb[2][CHUNK * COLS];
  __shared__ float abuf[2][64];
  __shared__ float bbuf[2][64];
  const int bid = blockIdx.x;
  const int bh = bid & 31, g = bid >> 5;
  const int b = bh >> 4, h = bh & 15;
  const int tid = threadIdx.x;
  const int cl = tid >> 4, li = tid & 15, lane = tid & 63, wid = tid >> 6;
  const int col = g * COLS + cl, d0 = li * 8;
  const size_t bh_qk = ((size_t)b * T_LEN * H_N + h) * DK;
  const size_t bh_v = ((size_t)b * T_LEN * H_N + h) * DV;
  const size_t bh_ab = (size_t)b * T_LEN * H_N + h;
  const int fo0 = wid * 2048 + lane * 16, fo1 = fo0 + 1024;
  const char* kg0 = (const char*)(k + bh_qk) + (size_t)(fo0 >> 9) * STEP_B + (fo0 & 511);
  const char* kg1 = (const char*)(k + bh_qk) + (size_t)(fo1 >> 9) * STEP_B + (fo1 & 511);
  const char* qg0 = (const char*)(q + bh_qk) + (size_t)(fo0 >> 9) * STEP_B + (fo0 & 511);
  const char* qg1 = (const char*)(q + bh_qk) + (size_t)(fo1 >> 9) * STEP_B + (fo1 & 511);
  const int fv = lane * 16;
  const char* vg = (const char*)(v + bh_v + g * COLS) + (size_t)(fv >> 6) * STEP_B + (fv & 63);
  const int lcl = lane < 16 ? lane : 15;
  const char* ag = (const char*)(al + bh_ab) + (size_t)lcl * AB_B;
  const char* bg = (const char*)(be + bh_ab) + (size_t)lcl * AB_B;
#define STAGEF(CI, P) do { \
    const size_t off = (size_t)(CI) * (CHUNK * STEP_B); \
    const size_t offab = (size_t)(CI) * (CHUNK * AB_B); \
    GLDS16(kg0 + off, &kb[P][wid * 512]); GLDS16(kg1 + off, &kb[P][wid * 512 + 256]); \
    GLDS16(qg0 + off, &qb[P][wid * 512]); GLDS16(qg1 + off, &qb[P][wid * 512 + 256]); \
    if (wid == 0) GLDS16(vg + off, &vb[P][0]); \
    else if (wid == 1) GLDS4(ag + offab, &abuf[P][0]); \
    else if (wid == 2) GLDS4(bg + offab, &bbuf[P][0]); \
  } while (0)
  float sv[8];
  const float* s0p = S0 + ((size_t)(b * H_N + h) * DK + d0) * DV + col;
#pragma unroll
  for (int j = 0; j < 8; ++j) sv[j] = s0p[(size_t)j * DV];
  STAGEF(0, 0);
  __syncthreads();
  float* op = out + bh_v + col;
  for (int ci = 0; ci < T_LEN / CHUNK; ++ci) {
    const int p = ci & 1;
    if (ci + 1 < T_LEN / CHUNK) STAGEF(ci + 1, p ^ 1);
    const float* kc = kb[p]; const float* qc = qb[p]; const float* vc = vb[p];
    const float* ac = abuf[p]; const float* bc = bbuf[p];
#pragma unroll
    for (int j = 0; j < CHUNK; ++j) {
      f32x4 kA = *(const f32x4*)(kc + j * DK + d0);
      f32x4 kB = *(const f32x4*)(kc + j * DK + d0 + 4);
      f32x4 qA = *(const f32x4*)(qc + j * DK + d0);
      f32x4 qB = *(const f32x4*)(qc + j * DK + d0 + 4);
      float vv = vc[j * COLS + cl], aa = ac[j], bv = bc[j];
      float kk[8] = {kA[0], kA[1], kA[2], kA[3], kB[0], kB[1], kB[2], kB[3]};
      float qq[8] = {qA[0], qA[1], qA[2], qA[3], qB[0], qB[1], qB[2], qB[3]};
      float pk0 = kk[0] * sv[0], pk1 = kk[1] * sv[1];
      float pu0 = qq[0] * sv[0], pu1 = qq[1] * sv[1];
      float pg0 = kk[0] * qq[0], pg1 = kk[1] * qq[1];
#pragma unroll
      for (int m = 2; m < 8; m += 2) {
        pk0 = fmaf(kk[m], sv[m], pk0); pk1 = fmaf(kk[m + 1], sv[m + 1], pk1);
        pu0 = fmaf(qq[m], sv[m], pu0); pu1 = fmaf(qq[m + 1], sv[m + 1], pu1);
        pg0 = fmaf(kk[m], qq[m], pg0); pg1 = fmaf(kk[m + 1], qq[m + 1], pg1);
      }
      float pk = red16(pk0 + pk1), pu = red16(pu0 + pu1), pg = red16(pg0 + pg1);
      float tmp = fmaf(-(bv * aa), pk, bv * vv);
#pragma unroll
      for (int m = 0; m < 8; ++m) sv[m] = fmaf(aa, sv[m], kk[m] * tmp);
      if (li == 0) op[(size_t)(ci * CHUNK + j) * OSTRIDE] = fmaf(pg, tmp, aa * pu);
    }
    __syncthreads();
  }
  float* sf = out + (size_t)2 * T_LEN * H_N * DV + ((size_t)(b * H_N + h) * DK + d0) * DV + col;
#pragma unroll
  for (int j = 0; j < 8; ++j) sf[(size_t)j * DV] = sv[j];
}

extern "C" void kernel_launch(void* const* d_in, const int* in_sizes, int n_in,
                              void* d_out, int out_size, void* d_ws,
                              size_t ws_size, hipStream_t stream) {
  const float* q = (const float*)d_in[0];
  const float* k = (const float*)d_in[1];
  const float* v = (const float*)d_in[2];
  const float* al = (const float*)d_in[3];
  const float* be = (const float*)d_in[4];
  const float* S0 = (const float*)d_in[5];
  float* out = (float*)d_out;

  if (ws_size >= WS_NEED) {
    gdn_p1<<<dim3(2048), dim3(256), 0, stream>>>(q, k, v, al, be, (char*)d_ws);
    gdn_p2<<<dim3(256), dim3(512), 0, stream>>>(S0, out, (const char*)d_ws);
  } else {
    gdn_fallback<<<dim3(256), dim3(256), 0, stream>>>(q, k, v, al, be, S0, out);
  }
}